// Round 11
// baseline (3280.486 us; speedup 1.0000x reference)
//
#include <hip/hip_runtime.h>
#include <hip/hip_bf16.h>
#include <math.h>

#define MIN_D (-3.402823466e+38f)

constexpr int Bb = 2, Ss = 2048, Dm = 1024, Hh = 16, HDd = 64, NV = 8192, DRr = 128;
constexpr int Mrows = Bb * Ss;   // 4096
constexpr float MARGIN = 0.01f;  // ~22 sigma of bf16 sim error (4.5e-4)
constexpr int CAP = 2097152;     // candidate-pair buffer (8MB)
constexpr float C2 = 0.18033688011112042f;   // 0.125 * log2(e)

typedef __attribute__((ext_vector_type(8))) short bf16x8;
typedef __attribute__((ext_vector_type(4))) float f32x4;

__device__ inline unsigned short f2bf(float x) {
    union { float f; unsigned u; } v; v.f = x;
    unsigned r = v.u + 0x7fff + ((v.u >> 16) & 1);   // RNE
    return (unsigned short)(r >> 16);
}
__device__ inline float bf2f(unsigned short u) {
    union { unsigned u; float f; } v; v.u = ((unsigned)u) << 16;
    return v.f;
}
__device__ inline unsigned pk_bf16(float a, float b) {   // native cvt_pk
    float2 t; t.x = a; t.y = b;
    __hip_bfloat162 h = __float22bfloat162_rn(t);
    return *(unsigned*)&h;
}

// Wave-aggregated candidate push: ONE atomicAdd per nonzero ballot (G12).
__device__ inline void push_pair(bool pred, unsigned enc,
                                 unsigned* __restrict__ cnt,
                                 unsigned* __restrict__ pairs)
{
    unsigned long long mask = __ballot(pred);
    if (mask) {                              // wave-uniform condition
        const int lane = threadIdx.x & 63;
        const int leader = __ffsll((long long)mask) - 1;
        unsigned base = 0;
        if (lane == leader) base = atomicAdd(cnt, (unsigned)__popcll(mask));
        base = (unsigned)__shfl((int)base, leader);
        if (pred) {
            unsigned off = (unsigned)__popcll(mask & ((1ull << lane) - 1ull));
            unsigned slot = base + off;
            if (slot < (unsigned)CAP) pairs[slot] = enc;
        }
    }
}

// ---------------------------------------------------------------------------
// f32 -> bf16 elementwise. 8 elems/thread; grid = n/2048.
// ---------------------------------------------------------------------------
__global__ __launch_bounds__(256)
void cvt_bf16(const float* __restrict__ x, unsigned short* __restrict__ y)
{
    size_t i = ((size_t)blockIdx.x * 256 + threadIdx.x) * 8;
    float4 a = *(const float4*)(x + i);
    float4 b = *(const float4*)(x + i + 4);
    uint4 p;
    p.x = pk_bf16(a.x, a.y);
    p.y = pk_bf16(a.z, a.w);
    p.z = pk_bf16(b.x, b.y);
    p.w = pk_bf16(b.z, b.w);
    *(uint4*)(y + i) = p;
}

// ---------------------------------------------------------------------------
// Fused transpose+convert of the three 1024x1024 weights (z selects).
// ---------------------------------------------------------------------------
__global__ __launch_bounds__(256)
void transpose_cvt3(const float* __restrict__ W0, const float* __restrict__ W1,
                    const float* __restrict__ W2, unsigned short* __restrict__ T0,
                    unsigned short* __restrict__ T1, unsigned short* __restrict__ T2)
{
    const float* W = blockIdx.z == 0 ? W0 : (blockIdx.z == 1 ? W1 : W2);
    unsigned short* WT = blockIdx.z == 0 ? T0 : (blockIdx.z == 1 ? T1 : T2);
    __shared__ unsigned short T[64][72];
    const int tid = threadIdx.x;
    const int n0 = blockIdx.x * 64, k0 = blockIdx.y * 64;
    const int rr = tid >> 4, cc = tid & 15;
#pragma unroll
    for (int q2 = 0; q2 < 4; ++q2) {
        int kk = rr * 4 + q2;
        float4 v = *(const float4*)(W + (size_t)(k0 + kk) * Dm + n0 + cc * 4);
        T[cc * 4 + 0][kk] = f2bf(v.x);
        T[cc * 4 + 1][kk] = f2bf(v.y);
        T[cc * 4 + 2][kk] = f2bf(v.z);
        T[cc * 4 + 3][kk] = f2bf(v.w);
    }
    __syncthreads();
#pragma unroll
    for (int q2 = 0; q2 < 4; ++q2) {
        int nn = rr * 4 + q2;
        uint2 u;
        u.x = (unsigned)T[nn][cc * 4 + 0] | ((unsigned)T[nn][cc * 4 + 1] << 16);
        u.y = (unsigned)T[nn][cc * 4 + 2] | ((unsigned)T[nn][cc * 4 + 3] << 16);
        *(uint2*)(WT + (size_t)(n0 + nn) * Dm + k0 + cc * 4) = u;
    }
}

// ---------------------------------------------------------------------------
// bf16 MFMA GEMM, 128x128 tile, 512 thr = 8 waves (2m x 4n), BK=32.
// Dual-target via blockIdx.z.
// ---------------------------------------------------------------------------
template<bool BF16OUT>
__global__ __launch_bounds__(512)
void gemm_bf16(const unsigned short* __restrict__ A,
               const unsigned short* BT0, const unsigned short* BT1,
               const float* bias0, const float* bias1,
               void* C0, void* C1, int N, int K)
{
    const unsigned short* BT = blockIdx.z ? BT1 : BT0;
    const float* bias = blockIdx.z ? bias1 : bias0;
    void* C = blockIdx.z ? C1 : C0;
    __shared__ __align__(16) unsigned short As[128 * 32];
    __shared__ __align__(16) unsigned short Bs[128 * 32];
    const int tid = threadIdx.x;
    const int l = tid & 63, w = tid >> 6;
    const int l15 = l & 15, l4 = l >> 4;
    const int wm = w >> 2, wn = w & 3;           // 2 x 4 wave grid
    const int row0 = blockIdx.y * 128, col0 = blockIdx.x * 128;

    f32x4 acc[4][2];
#pragma unroll
    for (int mi = 0; mi < 4; ++mi)
#pragma unroll
        for (int ni = 0; ni < 2; ++ni) acc[mi][ni] = (f32x4)(0.f);

    for (int k0 = 0; k0 < K; k0 += 32) {
        __syncthreads();
        {
            int r = tid >> 2, pc = tid & 3;
            uint4 vv = *(const uint4*)(A + (size_t)(row0 + r) * K + k0 + pc * 8);
            *(uint4*)&As[tid * 8] = vv;
        }
        {
            int r = tid >> 2, pc = tid & 3;
            uint4 vv = *(const uint4*)(BT + (size_t)(col0 + r) * K + k0 + pc * 8);
            *(uint4*)&Bs[tid * 8] = vv;
        }
        __syncthreads();

        bf16x8 af[4], bf[2];
#pragma unroll
        for (int mi = 0; mi < 4; ++mi)
            af[mi] = *(bf16x8*)&As[(wm * 64 + mi * 16 + l15) * 32 + l4 * 8];
#pragma unroll
        for (int ni = 0; ni < 2; ++ni)
            bf[ni] = *(bf16x8*)&Bs[(wn * 32 + ni * 16 + l15) * 32 + l4 * 8];
#pragma unroll
        for (int mi = 0; mi < 4; ++mi)
#pragma unroll
            for (int ni = 0; ni < 2; ++ni)
                acc[mi][ni] = __builtin_amdgcn_mfma_f32_16x16x32_bf16(af[mi], bf[ni], acc[mi][ni], 0, 0, 0);
    }

#pragma unroll
    for (int mi = 0; mi < 4; ++mi)
#pragma unroll
        for (int ni = 0; ni < 2; ++ni)
#pragma unroll
            for (int j = 0; j < 4; ++j) {
                int row = row0 + wm * 64 + mi * 16 + l4 * 4 + j;
                int col = col0 + wn * 32 + ni * 16 + l15;
                float vv = acc[mi][ni][j] + bias[col];
                if (BF16OUT)
                    ((unsigned short*)C)[(size_t)row * N + col] = f2bf(vv);
                else
                    ((float*)C)[(size_t)row * N + col] = vv;
            }
}

// ---------------------------------------------------------------------------
// Split-K f32 GEMM for vq: partial[z] = A[:, z*256:(z+1)*256] @ W-slice.
// ---------------------------------------------------------------------------
__global__ __launch_bounds__(256)
void gemm_vq_partial(const float* __restrict__ A, const float* __restrict__ W,
                     float* __restrict__ P)
{
    __shared__ float As[64][36];
    __shared__ float Ws[32][64];
    const int tid = threadIdx.x;
    const int row0 = blockIdx.y * 64, col0 = blockIdx.x * 64;
    const int kbase = blockIdx.z * 256;
    const int tr = tid >> 4, tc = tid & 15;
    float acc[4][4] = {};

    for (int k0 = kbase; k0 < kbase + 256; k0 += 32) {
        __syncthreads();
#pragma unroll
        for (int q2 = 0; q2 < 2; ++q2) {
            int oc = q2 * 256 + tid;
            int r = oc >> 3, c4 = (oc & 7) << 2;
            *(float4*)&As[r][c4] = *(const float4*)(A + (size_t)(row0 + r) * Dm + k0 + c4);
        }
#pragma unroll
        for (int q2 = 0; q2 < 2; ++q2) {
            int oc = q2 * 256 + tid;
            int r = oc >> 4, c4 = (oc & 15) << 2;
            *(float4*)&Ws[r][c4] = *(const float4*)(W + (size_t)(k0 + r) * DRr + col0 + c4);
        }
        __syncthreads();
#pragma unroll 8
        for (int kk = 0; kk < 32; ++kk) {
            float a[4];
#pragma unroll
            for (int i = 0; i < 4; ++i) a[i] = As[tr * 4 + i][kk];
            float4 bv = *(const float4*)&Ws[kk][tc * 4];
            float b[4] = {bv.x, bv.y, bv.z, bv.w};
#pragma unroll
            for (int i = 0; i < 4; ++i)
#pragma unroll
                for (int j = 0; j < 4; ++j)
                    acc[i][j] = fmaf(a[i], b[j], acc[i][j]);
        }
    }
    float* Pz = P + (size_t)blockIdx.z * Mrows * DRr;
#pragma unroll
    for (int i = 0; i < 4; ++i) {
        int r = row0 + tr * 4 + i;
        float4 ov = {acc[i][0], acc[i][1], acc[i][2], acc[i][3]};
        *(float4*)(Pz + (size_t)r * DRr + col0 + tc * 4) = ov;
    }
}

// ---------------------------------------------------------------------------
// Reduce split-K partials (fixed order) + bias -> vqb f32 and vq_hi bf16.
// ---------------------------------------------------------------------------
__global__ __launch_bounds__(256)
void reduce_vq(const float* __restrict__ P, const float* __restrict__ bias,
               float* __restrict__ vqb, unsigned short* __restrict__ vq_hi)
{
    const size_t i4 = ((size_t)blockIdx.x * 256 + threadIdx.x) * 4;
    const int col = (int)(i4 & 127);
    const size_t stride = (size_t)Mrows * DRr;
    float4 s = *(const float4*)(P + i4);
#pragma unroll
    for (int z = 1; z < 4; ++z) {
        float4 p = *(const float4*)(P + stride * z + i4);
        s.x += p.x; s.y += p.y; s.z += p.z; s.w += p.w;
    }
    float4 bv = *(const float4*)(bias + col);
    s.x += bv.x; s.y += bv.y; s.z += bv.z; s.w += bv.w;
    *(float4*)(vqb + i4) = s;
    uint2 u;
    u.x = pk_bf16(s.x, s.y);
    u.y = pk_bf16(s.z, s.w);
    *(uint2*)(vq_hi + i4) = u;
}

// ---------------------------------------------------------------------------
// SINGLE-PASS retrieval screen, A-resident col-sweep.
// Grid (16 col-groups x 512 keys, 32 row-tiles x 128 rows); 512 thr = 8 waves
// (4m x 2n). A-fragments (whole K=128) live in registers; B 64-key tiles
// double-buffered in LDS (32KB) with T14 reg-prefetch; 8 tiles/block,
// 16 MFMAs/wave/tile. Per tile: per-row running max (4 shuffles) ->
// push s >= runmax - MARGIN via wave-aggregated ballot (1 atomic/ballot).
// Capture guarantee: bf16(key*) >= runmax - 2*bferr >= runmax - MARGIN;
// exact f32 rescore re-ranks all pushes with first-index tie-break.
// ---------------------------------------------------------------------------
__global__ __launch_bounds__(512)
void sim_screen(const unsigned short* __restrict__ vq_hi,
                const unsigned short* __restrict__ vk_hi,
                unsigned* __restrict__ cnt, unsigned* __restrict__ pairs)
{
    __shared__ __align__(16) unsigned short Buf[2][64 * 128];   // 32KB dbuf
    const int tid = threadIdx.x;
    const int l = tid & 63, w = tid >> 6;
    const int l15 = l & 15, l4 = l >> 4;
    const int wm = w >> 1, wn = w & 1;           // 4m x 2n wave grid
    const int row0 = blockIdx.y * 128;
    const int key0 = blockIdx.x * 512;

    // A fragments in registers (whole K): af[mi][kk], k = kk*32 + l4*8 + i
    bf16x8 af[2][4];
#pragma unroll
    for (int mi = 0; mi < 2; ++mi) {
        const unsigned short* ap = vq_hi
            + (size_t)(row0 + wm * 32 + mi * 16 + l15) * 128 + l4 * 8;
#pragma unroll
        for (int kk = 0; kk < 4; ++kk)
            af[mi][kk] = *(const bf16x8*)(ap + kk * 32);
    }

    // stage B tile 0 (source chunk-XOR swizzled, LDS linear)
#pragma unroll
    for (int q2 = 0; q2 < 2; ++q2) {
        int oc = q2 * 512 + tid;
        int r = oc >> 4, pc = oc & 15;
        int lc = pc ^ (r & 15);
        uint4 vv = *(const uint4*)(vk_hi + (size_t)(key0 + r) * 128 + lc * 8);
        *(uint4*)&Buf[0][oc * 8] = vv;
    }
    __syncthreads();

    float rmax[2][4];
#pragma unroll
    for (int mi = 0; mi < 2; ++mi)
#pragma unroll
        for (int j = 0; j < 4; ++j) rmax[mi][j] = -INFINITY;

    for (int t = 0; t < 8; ++t) {
        const int cur = t & 1;
        // T14: issue next tile's loads into registers before compute
        uint4 st[2];
        if (t + 1 < 8) {
#pragma unroll
            for (int q2 = 0; q2 < 2; ++q2) {
                int oc = q2 * 512 + tid;
                int r = oc >> 4, pc = oc & 15;
                int lc = pc ^ (r & 15);
                st[q2] = *(const uint4*)(vk_hi + (size_t)(key0 + (t + 1) * 64 + r) * 128 + lc * 8);
            }
        }
        // compute tile t: 16 MFMAs/wave
        f32x4 acc[2][2];
#pragma unroll
        for (int mi = 0; mi < 2; ++mi)
#pragma unroll
            for (int ni = 0; ni < 2; ++ni) acc[mi][ni] = (f32x4)(0.f);
#pragma unroll
        for (int ni = 0; ni < 2; ++ni) {
            const int key16 = wn * 32 + ni * 16 + l15;
            bf16x8 bfr[4];
#pragma unroll
            for (int kk = 0; kk < 4; ++kk)
                bfr[kk] = *(bf16x8*)&Buf[cur][key16 * 128 + (((kk * 4 + l4) ^ (key16 & 15)) * 8)];
#pragma unroll
            for (int mi = 0; mi < 2; ++mi)
#pragma unroll
                for (int kk = 0; kk < 4; ++kk)
                    acc[mi][ni] = __builtin_amdgcn_mfma_f32_16x16x32_bf16(af[mi][kk], bfr[kk], acc[mi][ni], 0, 0, 0);
        }
        // per-row tile max -> cross-l15 reduce -> running max
        float tm[2][4];
#pragma unroll
        for (int mi = 0; mi < 2; ++mi)
#pragma unroll
            for (int j = 0; j < 4; ++j)
                tm[mi][j] = fmaxf(acc[mi][0][j], acc[mi][1][j]);
#pragma unroll
        for (int off = 1; off < 16; off <<= 1)
#pragma unroll
            for (int mi = 0; mi < 2; ++mi)
#pragma unroll
                for (int j = 0; j < 4; ++j)
                    tm[mi][j] = fmaxf(tm[mi][j], __shfl_xor(tm[mi][j], off));
#pragma unroll
        for (int mi = 0; mi < 2; ++mi)
#pragma unroll
            for (int j = 0; j < 4; ++j)
                rmax[mi][j] = fmaxf(rmax[mi][j], tm[mi][j]);
        // pushes (ballot-aggregated; rare)
#pragma unroll
        for (int mi = 0; mi < 2; ++mi)
#pragma unroll
            for (int ni = 0; ni < 2; ++ni)
#pragma unroll
                for (int j = 0; j < 4; ++j) {
                    const bool pred = acc[mi][ni][j] >= rmax[mi][j] - MARGIN;
                    const unsigned row = row0 + wm * 32 + mi * 16 + l4 * 4 + j;
                    const unsigned col = key0 + t * 64 + wn * 32 + ni * 16 + l15;
                    push_pair(pred, (row << 13) | col, cnt, pairs);
                }
        // write prefetched tile into the other buffer
        if (t + 1 < 8) {
#pragma unroll
            for (int q2 = 0; q2 < 2; ++q2) {
                int oc = q2 * 512 + tid;
                *(uint4*)&Buf[cur ^ 1][oc * 8] = st[q2];
            }
        }
        __syncthreads();
    }
}

// ---------------------------------------------------------------------------
// Exact f32 rescore; first-index argmax via u64 atomicMax.
// ---------------------------------------------------------------------------
__global__ __launch_bounds__(256)
void sim_rescore(const unsigned* __restrict__ pairs, const unsigned* __restrict__ cnt,
                 const float* __restrict__ vq, const float* __restrict__ vkeys,
                 unsigned long long* __restrict__ best)
{
    const int l = threadIdx.x & 63;
    const unsigned wav = (blockIdx.x * 256 + threadIdx.x) >> 6;
    const unsigned nw = (gridDim.x * 256) >> 6;
    const unsigned n = min(*cnt, (unsigned)CAP);
    for (unsigned i = wav; i < n; i += nw) {
        unsigned p = pairs[i];
        unsigned row = p >> 13, key = p & 8191u;
        float2 a = *(const float2*)(vq + (size_t)row * 128 + l * 2);
        float2 b = *(const float2*)(vkeys + (size_t)key * 128 + l * 2);
        float d = a.x * b.x + a.y * b.y;
#pragma unroll
        for (int off = 32; off; off >>= 1) d += __shfl_xor(d, off);
        if (l == 0) {
            unsigned fb = __float_as_uint(d);
            fb = (fb & 0x80000000u) ? ~fb : (fb | 0x80000000u);
            unsigned long long enc = ((unsigned long long)fb << 32) | (unsigned)(~key);
            atomicMax(best + row, enc);
        }
    }
}

// ---------------------------------------------------------------------------
// Fused build + transpose: VT[(b*16+h)*64 + d][key] = bf16(hs * vembed[idx]).
// ---------------------------------------------------------------------------
__global__ __launch_bounds__(256)
void build_vt(const float* __restrict__ hs, const float* __restrict__ vembed,
              const unsigned long long* __restrict__ best,
              unsigned short* __restrict__ vt)
{
    __shared__ unsigned short T[64][73];
    __shared__ int ids[64];
    const int tid = threadIdx.x;
    const int kt = blockIdx.x;
    const int bh = blockIdx.y;
    const int b = bh >> 4, h = bh & 15;
    if (tid < 64) {
        int row = b * Ss + kt * 64 + tid;
        ids[tid] = (int)((~(unsigned)(best[row] & 0xFFFFFFFFull)) & 8191u);
    }
    __syncthreads();
    {
        int r = tid >> 2, c16 = (tid & 3) * 16;
        size_t hrow = (size_t)(b * Ss + kt * 64 + r) * Dm + h * HDd + c16;
        size_t erow = (size_t)ids[r] * Dm + h * HDd + c16;
#pragma unroll
        for (int q2 = 0; q2 < 4; ++q2) {
            float4 a = *(const float4*)(hs + hrow + q2 * 4);
            float4 e = *(const float4*)(vembed + erow + q2 * 4);
            T[r][c16 + q2 * 4 + 0] = f2bf(a.x * e.x);
            T[r][c16 + q2 * 4 + 1] = f2bf(a.y * e.y);
            T[r][c16 + q2 * 4 + 2] = f2bf(a.z * e.z);
            T[r][c16 + q2 * 4 + 3] = f2bf(a.w * e.w);
        }
    }
    __syncthreads();
    {
        int d = tid >> 2, kc = (tid & 3) * 16;
        unsigned short ob[16];
#pragma unroll
        for (int i = 0; i < 16; ++i) ob[i] = T[kc + i][d];
        unsigned short* op = vt + ((size_t)(b * Hh + h) * HDd + d) * Ss + kt * 64 + kc;
        *(uint4*)op = *(uint4*)&ob[0];
        *(uint4*)(op + 8) = *(uint4*)&ob[8];
    }
}

// ---------------------------------------------------------------------------
// meanv[b][h*64+d] from VT row sums (fully-masked-row substitution value).
// ---------------------------------------------------------------------------
__global__ __launch_bounds__(256)
void mean_vt(const unsigned short* __restrict__ vt, float* __restrict__ mv)
{
    const int bh = blockIdx.x;
    const int b = bh >> 4, h = bh & 15;
    const int d = threadIdx.x >> 2, part = threadIdx.x & 3;
    const unsigned short* row = vt + ((size_t)bh * HDd + d) * Ss + part * 512;
    float s = 0.f;
    for (int j = 0; j < 512; j += 8) {
        uint4 u = *(const uint4*)(row + j);
        const unsigned uu[4] = {u.x, u.y, u.z, u.w};
#pragma unroll
        for (int m = 0; m < 4; ++m) {
            s += bf2f((unsigned short)(uu[m] & 0xffff));
            s += bf2f((unsigned short)(uu[m] >> 16));
        }
    }
    s += __shfl_xor(s, 1);
    s += __shfl_xor(s, 2);
    if (part == 0) mv[b * Dm + h * HDd + d] = s * (1.f / 2048.f);
}

// ---------------------------------------------------------------------------
// bf16 MFMA flash attention v4 (unchanged): QBLK=128/8 waves, swapped QK^T,
// pre-transposed V, log2 softmax + defer-rescale, balanced qt pairing.
// ---------------------------------------------------------------------------
__global__ __launch_bounds__(512)
void attn_mfma4(const unsigned short* __restrict__ q, const unsigned short* __restrict__ k,
                const unsigned short* __restrict__ vt, const float* __restrict__ am,
                const float* __restrict__ dmask, const float* __restrict__ meanv,
                unsigned short* __restrict__ o)
{
    __shared__ __align__(16) unsigned char smem[40960]; // K 8K | VT 8K | P 16K | amdm 8K
    __shared__ float uniflag[128];
    unsigned char* Ksm = smem;
    unsigned char* Vsm = smem + 8192;
    unsigned char* Psm = smem + 16384;
    float* amdmf = (float*)(smem + 32768);

    const int tid = threadIdx.x;
    const int l = tid & 63, w = tid >> 6;
    const int l15 = l & 15, l4 = l >> 4;
    const int lin = blockIdx.x + (blockIdx.y << 4) + (blockIdx.z << 8);
    const int half = lin >> 8, rem = lin & 255;
    const int qtb = rem & 15;
    const int qt = half ? (15 - qtb) : qtb;
    const int h = rem >> 4;
    const int b = half;
    const int row0 = qt * 128;

    {
        int j = tid * 4;
        float4 a = *(const float4*)(am + b * Ss + j);
        float4 d = *(const float4*)(dmask + h * Ss + j);
        float4 m;
        m.x = (a.x * d.x == 0.f) ? MIN_D : 0.f;
        m.y = (a.y * d.y == 0.f) ? MIN_D : 0.f;
        m.z = (a.z * d.z == 0.f) ? MIN_D : 0.f;
        m.w = (a.w * d.w == 0.f) ? MIN_D : 0.f;
        *(float4*)&amdmf[j] = m;
    }

    const int qloc = w * 16 + l15;
    const int qrow = row0 + qloc;
    bf16x8 qf[2];
    {
        const unsigned short* qp = q + ((size_t)(b * Ss + qrow)) * Dm + h * HDd + l4 * 8;
        qf[0] = *(const bf16x8*)qp;
        qf[1] = *(const bf16x8*)(qp + 32);
    }

    f32x4 acc[4];
#pragma unroll
    for (int d2 = 0; d2 < 4; ++d2) acc[d2] = (f32x4)(0.f);
    float mrun = -INFINITY, lrun = 0.f;
    const int ktmax = 2 * qt + 1;

    for (int kt = 0; kt <= ktmax; ++kt) {
        __syncthreads();
        {
            int key = tid >> 3, pc = tid & 7, lc = pc ^ (key & 7);
            uint4 vv = *(const uint4*)(k + ((size_t)(b * Ss + kt * 64 + key)) * Dm
                                       + h * HDd + lc * 8);
            *(uint4*)&Ksm[tid * 16] = vv;
        }
        {
            int d = tid >> 3, pc = tid & 7, lc = pc ^ (d & 7);
            uint4 vv = *(const uint4*)(vt + ((size_t)(b * Hh + h) * HDd + d) * Ss
                                       + kt * 64 + lc * 8);
            *(uint4*)&Vsm[tid * 16] = vv;
        }
        __syncthreads();

        f32x4 sreg[4];
#pragma unroll
        for (int kb = 0; kb < 4; ++kb) {
            const int key16 = kb * 16 + l15;
            const int sw = key16 & 7;
            bf16x8 k0 = *(bf16x8*)&Ksm[key16 * 128 + ((l4 ^ sw) * 16)];
            bf16x8 k1 = *(bf16x8*)&Ksm[key16 * 128 + (((4 + l4) ^ sw) * 16)];
            f32x4 s = (f32x4)(0.f);
            s = __builtin_amdgcn_mfma_f32_16x16x32_bf16(k0, qf[0], s, 0, 0, 0);
            s = __builtin_amdgcn_mfma_f32_16x16x32_bf16(k1, qf[1], s, 0, 0, 0);
            sreg[kb] = s;
        }

        float sv[16];
#pragma unroll
        for (int kb = 0; kb < 4; ++kb)
#pragma unroll
            for (int r = 0; r < 4; ++r) {
                const int key = kt * 64 + kb * 16 + l4 * 4 + r;
                const float mval = (key > qrow) ? MIN_D : amdmf[key];
                sv[kb * 4 + r] = fmaf(sreg[kb][r], C2, mval);
            }

        float pm = fmaxf(fmaxf(sv[0], sv[1]), sv[2]);
        pm = fmaxf(fmaxf(pm, sv[3]), fmaxf(sv[4], sv[5]));
        pm = fmaxf(fmaxf(pm, sv[6]), fmaxf(sv[7], sv[8]));
        pm = fmaxf(fmaxf(pm, sv[9]), fmaxf(sv[10], sv[11]));
        pm = fmaxf(fmaxf(pm, sv[12]), fmaxf(sv[13], sv[14]));
        pm = fmaxf(pm, sv[15]);
        pm = fmaxf(pm, __shfl_xor(pm, 16));
        pm = fmaxf(pm, __shfl_xor(pm, 32));

        if (__any(pm > mrun + 8.f)) {
            const float mn = fmaxf(mrun, pm);
            const float sc = __builtin_amdgcn_exp2f(mrun - mn);
            lrun *= sc;
#pragma unroll
            for (int d2 = 0; d2 < 4; ++d2) acc[d2] *= sc;
            mrun = mn;
        }

        float p[16], rs = 0.f;
#pragma unroll
        for (int i = 0; i < 16; ++i) {
            p[i] = __builtin_amdgcn_exp2f(sv[i] - mrun);
            rs += p[i];
        }
        rs += __shfl_xor(rs, 16);
        rs += __shfl_xor(rs, 32);
        lrun += rs;

        const unsigned pswz = (l15 & 7) << 4;
#pragma unroll
        for (int kb = 0; kb < 4; ++kb) {
            uint2 u;
            u.x = pk_bf16(p[kb * 4 + 0], p[kb * 4 + 1]);
            u.y = pk_bf16(p[kb * 4 + 2], p[kb * 4 + 3]);
            *(uint2*)&Psm[qloc * 128 + ((kb * 32 + l4 * 8) ^ pswz)] = u;
        }

#pragma unroll
        for (int ks = 0; ks < 2; ++ks) {
            bf16x8 pa = *(bf16x8*)&Psm[qloc * 128 + ((ks * 64 + l4 * 16) ^ pswz)];
#pragma unroll
            for (int d2 = 0; d2 < 4; ++d2) {
                const int dd = d2 * 16 + l15;
                bf16x8 vb = *(bf16x8*)&Vsm[dd * 128 + ((ks * 64 + l4 * 16) ^ ((dd & 7) << 4))];
                acc[d2] = __builtin_amdgcn_mfma_f32_16x16x32_bf16(vb, pa, acc[d2], 0, 0, 0);
            }
        }
    }

    const float inv = 1.f / lrun;
    const bool uni = (mrun <= -1e37f);
    __syncthreads();
    unsigned short* stg = (unsigned short*)smem;
    uniflag[qloc] = uni ? 1.f : 0.f;
#pragma unroll
    for (int d2 = 0; d2 < 4; ++d2) {
        uint2 u;
        u.x = pk_bf16(acc[d2][0] * inv, acc[d2][1] * inv);
        u.y = pk_bf16(acc[d2][2] * inv, acc[d2][3] * inv);
        *(uint2*)&stg[qloc * 72 + d2 * 16 + l4 * 4] = u;
    }
    __syncthreads();
    {
        const int r = tid >> 2, c16 = (tid & 3) * 16;
        const bool u = uniflag[r] != 0.f;
        uint4 o0, o1;
        if (u) {
            unsigned short ob[16];
#pragma unroll
            for (int i = 0; i < 16; ++i)
                ob[i] = f2bf(meanv[b * Dm + h * HDd + c16 + i]);
            o0 = *(uint4*)&ob[0];
            o1 = *(uint4*)&ob[8];
        } else {
            o0 = *(uint4*)&stg[r * 72 + c16];
            o1 = *(uint4*)&stg[r * 72 + c16 + 8];
        }
        unsigned short* op = o + ((size_t)(b * Ss + row0 + r)) * Dm + h * HDd + c16;
        *(uint4*)op = o0;
        *(uint4*)(op + 8) = o1;
    }
}

// ---------------------------------------------------------------------------
extern "C" void kernel_launch(void* const* d_in, const int* in_sizes, int n_in,
                              void* d_out, int out_size, void* d_ws, size_t ws_size,
                              hipStream_t stream)
{
    const float* hs     = (const float*)d_in[0];
    const float* amask  = (const float*)d_in[1];
    const float* Wq     = (const float*)d_in[2];
    const float* bq     = (const float*)d_in[3];
    const float* Wk     = (const float*)d_in[4];
    const float* bk     = (const float*)d_in[5];
    const float* dmask  = (const float*)d_in[6];
    const float* Wvq    = (const float*)d_in[7];
    const float* bvq    = (const float*)d_in[8];
    const float* vkeys  = (const float*)d_in[9];
    const float* vembed = (const float*)d_in[10];
    const float* Wo     = (const float*)d_in[11];
    const float* bo     = (const float*)d_in[12];
    float* out = (float*)d_out;

    char* w = (char*)d_ws;
    size_t off = 0;
    auto take = [&](size_t n) { char* p = w + off; off = (off + n + 255) & ~(size_t)255; return p; };
    unsigned short* hsbf  = (unsigned short*)take((size_t)Mrows * Dm * 2);
    unsigned short* WqT   = (unsigned short*)take((size_t)Dm * Dm * 2);
    unsigned short* WkT   = (unsigned short*)take((size_t)Dm * Dm * 2);
    unsigned short* WoT   = (unsigned short*)take((size_t)Dm * Dm * 2);
    unsigned short* qbf   = (unsigned short*)take((size_t)Mrows * Dm * 2);
    unsigned short* kbf   = (unsigned short*)take((size_t)Mrows * Dm * 2);
    unsigned short* vtb   = (unsigned short*)take((size_t)Mrows * Dm * 2);   // VT
    unsigned short* attno = (unsigned short*)take((size_t)Mrows * Dm * 2);
    float* vqp   = (float*)take((size_t)4 * Mrows * DRr * 4);               // split-K partials
    float* vqb   = (float*)take((size_t)Mrows * DRr * 4);
    unsigned short* vq_hi = (unsigned short*)take((size_t)Mrows * DRr * 2);
    unsigned short* vk_hi = (unsigned short*)take((size_t)NV * DRr * 2);
    unsigned* cnt = (unsigned*)take(256);
    unsigned* pairs = (unsigned*)take((size_t)CAP * 4);
    unsigned long long* best = (unsigned long long*)take((size_t)Mrows * 8);
    float* mvb   = (float*)take((size_t)Bb * Dm * 4);

    hipMemsetAsync(cnt, 0, 4, stream);
    hipMemsetAsync(best, 0, (size_t)Mrows * 8, stream);

    dim3 blk(256);
    // dtype prep
    cvt_bf16<<<dim3(Mrows * Dm / 2048), blk, 0, stream>>>(hs, hsbf);
    transpose_cvt3<<<dim3(Dm / 64, Dm / 64, 3), blk, 0, stream>>>(Wq, Wk, Wo, WqT, WkT, WoT);
    // Q,K projections fused via z
    gemm_bf16<true><<<dim3(Dm / 128, Mrows / 128, 2), dim3(512), 0, stream>>>(
        hsbf, WqT, WkT, bq, bk, qbf, kbf, Dm, Dm);
    // retrieval: split-K exact vq, reduce(+bf16 copy), single-pass screen, rescore
    gemm_vq_partial<<<dim3(DRr / 64, Mrows / 64, 4), blk, 0, stream>>>(hs, Wvq, vqp);
    reduce_vq<<<dim3(Mrows * DRr / 1024), blk, 0, stream>>>(vqp, bvq, vqb, vq_hi);
    cvt_bf16<<<dim3(NV * DRr / 2048), blk, 0, stream>>>(vkeys, vk_hi);
    sim_screen<<<dim3(NV / 512, Mrows / 128), dim3(512), 0, stream>>>(vq_hi, vk_hi, cnt, pairs);
    sim_rescore<<<dim3(1024), blk, 0, stream>>>(pairs, cnt, vqb, vkeys, best);
    // fused build+transpose of V, then mean
    build_vt<<<dim3(Ss / 64, Bb * Hh), blk, 0, stream>>>(hs, vembed, best, vtb);
    mean_vt<<<dim3(Bb * Hh), blk, 0, stream>>>(vtb, mvb);
    // attention (512 threads)
    attn_mfma4<<<dim3(Ss / 128, Hh, Bb), dim3(512), 0, stream>>>(
        qbf, kbf, vtb, amask, dmask, mvb, attno);
    // output projection (f32 out)
    gemm_bf16<false><<<dim3(Dm / 128, Mrows / 128, 1), dim3(512), 0, stream>>>(
        attno, WoT, WoT, bo, bo, out, out, Dm, Dm);
}

// Round 12
// 389.357 us; speedup vs baseline: 8.4254x; 8.4254x over previous
//
#include <hip/hip_runtime.h>
#include <hip/hip_bf16.h>
#include <math.h>

#define MIN_D (-3.402823466e+38f)

constexpr int Bb = 2, Ss = 2048, Dm = 1024, Hh = 16, HDd = 64, NV = 8192, DRr = 128;
constexpr int Mrows = Bb * Ss;   // 4096
constexpr float MARGIN = 0.01f;  // >> 2x bf16-MFMA sim error (~1e-3 RSS)
constexpr float C2 = 0.18033688011112042f;   // 0.125 * log2(e)

typedef __attribute__((ext_vector_type(8))) short bf16x8;
typedef __attribute__((ext_vector_type(4))) float f32x4;

__device__ inline unsigned short f2bf(float x) {
    union { float f; unsigned u; } v; v.f = x;
    unsigned r = v.u + 0x7fff + ((v.u >> 16) & 1);   // RNE
    return (unsigned short)(r >> 16);
}
__device__ inline float bf2f(unsigned short u) {
    union { unsigned u; float f; } v; v.u = ((unsigned)u) << 16;
    return v.f;
}
__device__ inline unsigned pk_bf16(float a, float b) {   // native cvt_pk
    float2 t; t.x = a; t.y = b;
    __hip_bfloat162 h = __float22bfloat162_rn(t);
    return *(unsigned*)&h;
}

// ---------------------------------------------------------------------------
// f32 -> bf16 elementwise. 8 elems/thread; grid = n/2048.
// ---------------------------------------------------------------------------
__global__ __launch_bounds__(256)
void cvt_bf16(const float* __restrict__ x, unsigned short* __restrict__ y)
{
    size_t i = ((size_t)blockIdx.x * 256 + threadIdx.x) * 8;
    float4 a = *(const float4*)(x + i);
    float4 b = *(const float4*)(x + i + 4);
    uint4 p;
    p.x = pk_bf16(a.x, a.y);
    p.y = pk_bf16(a.z, a.w);
    p.z = pk_bf16(b.x, b.y);
    p.w = pk_bf16(b.z, b.w);
    *(uint4*)(y + i) = p;
}

// ---------------------------------------------------------------------------
// Fused transpose+convert of the three 1024x1024 weights (z selects).
// ---------------------------------------------------------------------------
__global__ __launch_bounds__(256)
void transpose_cvt3(const float* __restrict__ W0, const float* __restrict__ W1,
                    const float* __restrict__ W2, unsigned short* __restrict__ T0,
                    unsigned short* __restrict__ T1, unsigned short* __restrict__ T2)
{
    const float* W = blockIdx.z == 0 ? W0 : (blockIdx.z == 1 ? W1 : W2);
    unsigned short* WT = blockIdx.z == 0 ? T0 : (blockIdx.z == 1 ? T1 : T2);
    __shared__ unsigned short T[64][72];
    const int tid = threadIdx.x;
    const int n0 = blockIdx.x * 64, k0 = blockIdx.y * 64;
    const int rr = tid >> 4, cc = tid & 15;
#pragma unroll
    for (int q2 = 0; q2 < 4; ++q2) {
        int kk = rr * 4 + q2;
        float4 v = *(const float4*)(W + (size_t)(k0 + kk) * Dm + n0 + cc * 4);
        T[cc * 4 + 0][kk] = f2bf(v.x);
        T[cc * 4 + 1][kk] = f2bf(v.y);
        T[cc * 4 + 2][kk] = f2bf(v.z);
        T[cc * 4 + 3][kk] = f2bf(v.w);
    }
    __syncthreads();
#pragma unroll
    for (int q2 = 0; q2 < 4; ++q2) {
        int nn = rr * 4 + q2;
        uint2 u;
        u.x = (unsigned)T[nn][cc * 4 + 0] | ((unsigned)T[nn][cc * 4 + 1] << 16);
        u.y = (unsigned)T[nn][cc * 4 + 2] | ((unsigned)T[nn][cc * 4 + 3] << 16);
        *(uint2*)(WT + (size_t)(n0 + nn) * Dm + k0 + cc * 4) = u;
    }
}

// ---------------------------------------------------------------------------
// bf16 MFMA GEMM, 128x128 tile, 512 thr = 8 waves (2m x 4n), BK=32.
// Dual-target via blockIdx.z. (Unchanged, proven.)
// ---------------------------------------------------------------------------
template<bool BF16OUT>
__global__ __launch_bounds__(512)
void gemm_bf16(const unsigned short* __restrict__ A,
               const unsigned short* BT0, const unsigned short* BT1,
               const float* bias0, const float* bias1,
               void* C0, void* C1, int N, int K)
{
    const unsigned short* BT = blockIdx.z ? BT1 : BT0;
    const float* bias = blockIdx.z ? bias1 : bias0;
    void* C = blockIdx.z ? C1 : C0;
    __shared__ __align__(16) unsigned short As[128 * 32];
    __shared__ __align__(16) unsigned short Bs[128 * 32];
    const int tid = threadIdx.x;
    const int l = tid & 63, w = tid >> 6;
    const int l15 = l & 15, l4 = l >> 4;
    const int wm = w >> 2, wn = w & 3;           // 2 x 4 wave grid
    const int row0 = blockIdx.y * 128, col0 = blockIdx.x * 128;

    f32x4 acc[4][2];
#pragma unroll
    for (int mi = 0; mi < 4; ++mi)
#pragma unroll
        for (int ni = 0; ni < 2; ++ni) acc[mi][ni] = (f32x4)(0.f);

    for (int k0 = 0; k0 < K; k0 += 32) {
        __syncthreads();
        {
            int r = tid >> 2, pc = tid & 3;
            uint4 vv = *(const uint4*)(A + (size_t)(row0 + r) * K + k0 + pc * 8);
            *(uint4*)&As[tid * 8] = vv;
        }
        {
            int r = tid >> 2, pc = tid & 3;
            uint4 vv = *(const uint4*)(BT + (size_t)(col0 + r) * K + k0 + pc * 8);
            *(uint4*)&Bs[tid * 8] = vv;
        }
        __syncthreads();

        bf16x8 af[4], bf[2];
#pragma unroll
        for (int mi = 0; mi < 4; ++mi)
            af[mi] = *(bf16x8*)&As[(wm * 64 + mi * 16 + l15) * 32 + l4 * 8];
#pragma unroll
        for (int ni = 0; ni < 2; ++ni)
            bf[ni] = *(bf16x8*)&Bs[(wn * 32 + ni * 16 + l15) * 32 + l4 * 8];
#pragma unroll
        for (int mi = 0; mi < 4; ++mi)
#pragma unroll
            for (int ni = 0; ni < 2; ++ni)
                acc[mi][ni] = __builtin_amdgcn_mfma_f32_16x16x32_bf16(af[mi], bf[ni], acc[mi][ni], 0, 0, 0);
    }

#pragma unroll
    for (int mi = 0; mi < 4; ++mi)
#pragma unroll
        for (int ni = 0; ni < 2; ++ni)
#pragma unroll
            for (int j = 0; j < 4; ++j) {
                int row = row0 + wm * 64 + mi * 16 + l4 * 4 + j;
                int col = col0 + wn * 32 + ni * 16 + l15;
                float vv = acc[mi][ni][j] + bias[col];
                if (BF16OUT)
                    ((unsigned short*)C)[(size_t)row * N + col] = f2bf(vv);
                else
                    ((float*)C)[(size_t)row * N + col] = vv;
            }
}

// ---------------------------------------------------------------------------
// Split-K f32 GEMM for vq: partial[z] = A[:, z*256:(z+1)*256] @ W-slice.
// ---------------------------------------------------------------------------
__global__ __launch_bounds__(256)
void gemm_vq_partial(const float* __restrict__ A, const float* __restrict__ W,
                     float* __restrict__ P)
{
    __shared__ float As[64][36];
    __shared__ float Ws[32][64];
    const int tid = threadIdx.x;
    const int row0 = blockIdx.y * 64, col0 = blockIdx.x * 64;
    const int kbase = blockIdx.z * 256;
    const int tr = tid >> 4, tc = tid & 15;
    float acc[4][4] = {};

    for (int k0 = kbase; k0 < kbase + 256; k0 += 32) {
        __syncthreads();
#pragma unroll
        for (int q2 = 0; q2 < 2; ++q2) {
            int oc = q2 * 256 + tid;
            int r = oc >> 3, c4 = (oc & 7) << 2;
            *(float4*)&As[r][c4] = *(const float4*)(A + (size_t)(row0 + r) * Dm + k0 + c4);
        }
#pragma unroll
        for (int q2 = 0; q2 < 2; ++q2) {
            int oc = q2 * 256 + tid;
            int r = oc >> 4, c4 = (oc & 15) << 2;
            *(float4*)&Ws[r][c4] = *(const float4*)(W + (size_t)(k0 + r) * DRr + col0 + c4);
        }
        __syncthreads();
#pragma unroll 8
        for (int kk = 0; kk < 32; ++kk) {
            float a[4];
#pragma unroll
            for (int i = 0; i < 4; ++i) a[i] = As[tr * 4 + i][kk];
            float4 bv = *(const float4*)&Ws[kk][tc * 4];
            float b[4] = {bv.x, bv.y, bv.z, bv.w};
#pragma unroll
            for (int i = 0; i < 4; ++i)
#pragma unroll
                for (int j = 0; j < 4; ++j)
                    acc[i][j] = fmaf(a[i], b[j], acc[i][j]);
        }
    }
    float* Pz = P + (size_t)blockIdx.z * Mrows * DRr;
#pragma unroll
    for (int i = 0; i < 4; ++i) {
        int r = row0 + tr * 4 + i;
        float4 ov = {acc[i][0], acc[i][1], acc[i][2], acc[i][3]};
        *(float4*)(Pz + (size_t)r * DRr + col0 + tc * 4) = ov;
    }
}

// ---------------------------------------------------------------------------
// Reduce split-K partials (fixed order) + bias -> vqb f32 and vq_hi bf16.
// ---------------------------------------------------------------------------
__global__ __launch_bounds__(256)
void reduce_vq(const float* __restrict__ P, const float* __restrict__ bias,
               float* __restrict__ vqb, unsigned short* __restrict__ vq_hi)
{
    const size_t i4 = ((size_t)blockIdx.x * 256 + threadIdx.x) * 4;
    const int col = (int)(i4 & 127);
    const size_t stride = (size_t)Mrows * DRr;
    float4 s = *(const float4*)(P + i4);
#pragma unroll
    for (int z = 1; z < 4; ++z) {
        float4 p = *(const float4*)(P + stride * z + i4);
        s.x += p.x; s.y += p.y; s.z += p.z; s.w += p.w;
    }
    float4 bv = *(const float4*)(bias + col);
    s.x += bv.x; s.y += bv.y; s.z += bv.z; s.w += bv.w;
    *(float4*)(vqb + i4) = s;
    uint2 u;
    u.x = pk_bf16(s.x, s.y);
    u.y = pk_bf16(s.z, s.w);
    *(uint2*)(vq_hi + i4) = u;
}

// ---------------------------------------------------------------------------
// Screen pass 0 (R10-proven GEMM structure + global_load_lds staging):
// per-(row, 128-key tile) bf16 maxima -> rtm[tile][row] (transposed layout).
// ---------------------------------------------------------------------------
__global__ __launch_bounds__(512)
void sim_gemm0(const unsigned short* __restrict__ A,
               const unsigned short* __restrict__ BT,
               float* __restrict__ rtm)
{
    __shared__ __align__(16) unsigned short As[128 * 32];
    __shared__ __align__(16) unsigned short Bs[128 * 32];
    __shared__ float red[128][4];
    const int tid = threadIdx.x;
    const int l = tid & 63, w = tid >> 6;
    const int l15 = l & 15, l4 = l >> 4;
    const int wm = w >> 2, wn = w & 3;
    const int row0 = blockIdx.y * 128, col0 = blockIdx.x * 128;

    f32x4 acc[4][2];
#pragma unroll
    for (int mi = 0; mi < 4; ++mi)
#pragma unroll
        for (int ni = 0; ni < 2; ++ni) acc[mi][ni] = (f32x4)(0.f);

    for (int k0 = 0; k0 < DRr; k0 += 32) {
        __syncthreads();
        {   // async global->LDS staging (m97 pattern; dest = base + lane*16)
            int r = tid >> 2, pc = tid & 3;
            __builtin_amdgcn_global_load_lds(
                (const __attribute__((address_space(1))) unsigned int*)(A + (size_t)(row0 + r) * DRr + k0 + pc * 8),
                (__attribute__((address_space(3))) unsigned int*)&As[tid * 8], 16, 0, 0);
            __builtin_amdgcn_global_load_lds(
                (const __attribute__((address_space(1))) unsigned int*)(BT + (size_t)(col0 + r) * DRr + k0 + pc * 8),
                (__attribute__((address_space(3))) unsigned int*)&Bs[tid * 8], 16, 0, 0);
        }
        __syncthreads();

        bf16x8 af[4], bf[2];
#pragma unroll
        for (int mi = 0; mi < 4; ++mi)
            af[mi] = *(bf16x8*)&As[(wm * 64 + mi * 16 + l15) * 32 + l4 * 8];
#pragma unroll
        for (int ni = 0; ni < 2; ++ni)
            bf[ni] = *(bf16x8*)&Bs[(wn * 32 + ni * 16 + l15) * 32 + l4 * 8];
#pragma unroll
        for (int mi = 0; mi < 4; ++mi)
#pragma unroll
            for (int ni = 0; ni < 2; ++ni)
                acc[mi][ni] = __builtin_amdgcn_mfma_f32_16x16x32_bf16(af[mi], bf[ni], acc[mi][ni], 0, 0, 0);
    }

    // per-row maxima over this block's 128 cols
    float rm[4][4];
#pragma unroll
    for (int mi = 0; mi < 4; ++mi)
#pragma unroll
        for (int j = 0; j < 4; ++j)
            rm[mi][j] = fmaxf(acc[mi][0][j], acc[mi][1][j]);
#pragma unroll
    for (int off = 1; off < 16; off <<= 1)
#pragma unroll
        for (int mi = 0; mi < 4; ++mi)
#pragma unroll
            for (int j = 0; j < 4; ++j)
                rm[mi][j] = fmaxf(rm[mi][j], __shfl_xor(rm[mi][j], off));
    if (l15 == 0) {
#pragma unroll
        for (int mi = 0; mi < 4; ++mi)
#pragma unroll
            for (int j = 0; j < 4; ++j)
                red[wm * 64 + mi * 16 + l4 * 4 + j][wn] = rm[mi][j];
    }
    __syncthreads();
    if (tid < 128) {
        float m = fmaxf(fmaxf(red[tid][0], red[tid][1]),
                        fmaxf(red[tid][2], red[tid][3]));
        rtm[(size_t)blockIdx.x * Mrows + row0 + tid] = m;
    }
}

// ---------------------------------------------------------------------------
// thr[row] = max over 64 tile-maxima - MARGIN (rtm transposed: [tile][row]).
// ---------------------------------------------------------------------------
__global__ __launch_bounds__(256)
void sim_combine2(const float* __restrict__ rtm, float* __restrict__ thr)
{
    int r = blockIdx.x * 256 + threadIdx.x;
    if (r >= Mrows) return;
    float m = -INFINITY;
#pragma unroll 8
    for (int c = 0; c < 64; ++c)
        m = fmaxf(m, rtm[(size_t)c * Mrows + r]);
    thr[r] = m - MARGIN;
}

// ---------------------------------------------------------------------------
// Exact f32 argmax over selected tiles, grouped by tile.
// Grid = 64 blocks (one per 128-key tile), 256 thr. vk tile staged f32 in LDS
// (transposed [d][k] -> conflict-free dot reads); rows with
// rtm[tile][row] >= thr[row] (avg ~1.05/row over all tiles) are listed, then
// each row's 128 exact dots computed and argmax-combined into best[] via
// u64 atomicMax (enc = flipfloat << 32 | ~key; first-index tie-break).
// Guarantee: the winning tile satisfies rtm >= thr (bf16 err << MARGIN).
// ---------------------------------------------------------------------------
__global__ __launch_bounds__(256)
void sim_exact(const float* __restrict__ rtm, const float* __restrict__ thr,
               const float* __restrict__ vq, const float* __restrict__ vkeys,
               unsigned long long* __restrict__ best)
{
    __shared__ float vkt[128][129];   // [d][k] f32, 66KB
    __shared__ float vqs[128];
    __shared__ float part[256];
    __shared__ int list[4096];
    __shared__ int lcnt;
    const int tid = threadIdx.x;
    const int tile = blockIdx.x;
    if (tid == 0) lcnt = 0;

    // stage vk tile transposed: idx enumerates (key, d4)
#pragma unroll
    for (int i = 0; i < 16; ++i) {
        int idx = i * 256 + tid;
        int k = idx >> 5, d4 = (idx & 31) * 4;
        float4 v = *(const float4*)(vkeys + (size_t)(tile * 128 + k) * 128 + d4);
        vkt[d4 + 0][k] = v.x;
        vkt[d4 + 1][k] = v.y;
        vkt[d4 + 2][k] = v.z;
        vkt[d4 + 3][k] = v.w;
    }
    __syncthreads();

    // build selected-row list
    for (int r = tid; r < Mrows; r += 256)
        if (rtm[(size_t)tile * Mrows + r] >= thr[r]) {
            int p = atomicAdd(&lcnt, 1);
            list[p] = r;
        }
    __syncthreads();
    const int n = lcnt;

    for (int i = 0; i < n; ++i) {
        const int row = list[i];
        if (tid < 32) {
            float4 v = *(const float4*)(vq + (size_t)row * 128 + tid * 4);
            *(float4*)&vqs[tid * 4] = v;
        }
        __syncthreads();
        // thread = (key k = tid&127, half h = tid>>7): dims [h*64, h*64+64)
        const int k = tid & 127, h = (tid >> 7) * 64;
        float s = 0.f;
#pragma unroll
        for (int d = 0; d < 64; ++d)
            s = fmaf(vqs[h + d], vkt[h + d][k], s);
        part[tid] = s;
        __syncthreads();
        if (tid < 64) {
            float s0 = part[tid] + part[tid + 128];
            float s1 = part[tid + 64] + part[tid + 192];
            float bs = s0; int bk = tid;
            if (s1 > s0) { bs = s1; bk = tid + 64; }
#pragma unroll
            for (int off = 1; off < 64; off <<= 1) {
                float os = __shfl_xor(bs, off);
                int ok = __shfl_xor(bk, off);
                if (os > bs || (os == bs && ok < bk)) { bs = os; bk = ok; }
            }
            if (tid == 0) {
                unsigned key = tile * 128 + bk;
                unsigned fb = __float_as_uint(bs);
                fb = (fb & 0x80000000u) ? ~fb : (fb | 0x80000000u);
                unsigned long long enc = ((unsigned long long)fb << 32) | (unsigned)(~key);
                atomicMax(best + row, enc);
            }
        }
        __syncthreads();
    }
}

// ---------------------------------------------------------------------------
// Fused build + transpose: VT[(b*16+h)*64 + d][key] = bf16(hs * vembed[idx]).
// ---------------------------------------------------------------------------
__global__ __launch_bounds__(256)
void build_vt(const float* __restrict__ hs, const float* __restrict__ vembed,
              const unsigned long long* __restrict__ best,
              unsigned short* __restrict__ vt)
{
    __shared__ unsigned short T[64][73];
    __shared__ int ids[64];
    const int tid = threadIdx.x;
    const int kt = blockIdx.x;
    const int bh = blockIdx.y;
    const int b = bh >> 4, h = bh & 15;
    if (tid < 64) {
        int row = b * Ss + kt * 64 + tid;
        ids[tid] = (int)((~(unsigned)(best[row] & 0xFFFFFFFFull)) & 8191u);
    }
    __syncthreads();
    {
        int r = tid >> 2, c16 = (tid & 3) * 16;
        size_t hrow = (size_t)(b * Ss + kt * 64 + r) * Dm + h * HDd + c16;
        size_t erow = (size_t)ids[r] * Dm + h * HDd + c16;
#pragma unroll
        for (int q2 = 0; q2 < 4; ++q2) {
            float4 a = *(const float4*)(hs + hrow + q2 * 4);
            float4 e = *(const float4*)(vembed + erow + q2 * 4);
            T[r][c16 + q2 * 4 + 0] = f2bf(a.x * e.x);
            T[r][c16 + q2 * 4 + 1] = f2bf(a.y * e.y);
            T[r][c16 + q2 * 4 + 2] = f2bf(a.z * e.z);
            T[r][c16 + q2 * 4 + 3] = f2bf(a.w * e.w);
        }
    }
    __syncthreads();
    {
        int d = tid >> 2, kc = (tid & 3) * 16;
        unsigned short ob[16];
#pragma unroll
        for (int i = 0; i < 16; ++i) ob[i] = T[kc + i][d];
        unsigned short* op = vt + ((size_t)(b * Hh + h) * HDd + d) * Ss + kt * 64 + kc;
        *(uint4*)op = *(uint4*)&ob[0];
        *(uint4*)(op + 8) = *(uint4*)&ob[8];
    }
}

// ---------------------------------------------------------------------------
// meanv[b][h*64+d] from VT row sums (fully-masked-row substitution value).
// ---------------------------------------------------------------------------
__global__ __launch_bounds__(256)
void mean_vt(const unsigned short* __restrict__ vt, float* __restrict__ mv)
{
    const int bh = blockIdx.x;
    const int b = bh >> 4, h = bh & 15;
    const int d = threadIdx.x >> 2, part = threadIdx.x & 3;
    const unsigned short* row = vt + ((size_t)bh * HDd + d) * Ss + part * 512;
    float s = 0.f;
    for (int j = 0; j < 512; j += 8) {
        uint4 u = *(const uint4*)(row + j);
        const unsigned uu[4] = {u.x, u.y, u.z, u.w};
#pragma unroll
        for (int m = 0; m < 4; ++m) {
            s += bf2f((unsigned short)(uu[m] & 0xffff));
            s += bf2f((unsigned short)(uu[m] >> 16));
        }
    }
    s += __shfl_xor(s, 1);
    s += __shfl_xor(s, 2);
    if (part == 0) mv[b * Dm + h * HDd + d] = s * (1.f / 2048.f);
}

// ---------------------------------------------------------------------------
// bf16 MFMA flash attention v4 (unchanged): QBLK=128/8 waves, swapped QK^T,
// pre-transposed V, log2 softmax + defer-rescale, balanced qt pairing.
// ---------------------------------------------------------------------------
__global__ __launch_bounds__(512)
void attn_mfma4(const unsigned short* __restrict__ q, const unsigned short* __restrict__ k,
                const unsigned short* __restrict__ vt, const float* __restrict__ am,
                const float* __restrict__ dmask, const float* __restrict__ meanv,
                unsigned short* __restrict__ o)
{
    __shared__ __align__(16) unsigned char smem[40960]; // K 8K | VT 8K | P 16K | amdm 8K
    __shared__ float uniflag[128];
    unsigned char* Ksm = smem;
    unsigned char* Vsm = smem + 8192;
    unsigned char* Psm = smem + 16384;
    float* amdmf = (float*)(smem + 32768);

    const int tid = threadIdx.x;
    const int l = tid & 63, w = tid >> 6;
    const int l15 = l & 15, l4 = l >> 4;
    const int lin = blockIdx.x + (blockIdx.y << 4) + (blockIdx.z << 8);
    const int half = lin >> 8, rem = lin & 255;
    const int qtb = rem & 15;
    const int qt = half ? (15 - qtb) : qtb;
    const int h = rem >> 4;
    const int b = half;
    const int row0 = qt * 128;

    {
        int j = tid * 4;
        float4 a = *(const float4*)(am + b * Ss + j);
        float4 d = *(const float4*)(dmask + h * Ss + j);
        float4 m;
        m.x = (a.x * d.x == 0.f) ? MIN_D : 0.f;
        m.y = (a.y * d.y == 0.f) ? MIN_D : 0.f;
        m.z = (a.z * d.z == 0.f) ? MIN_D : 0.f;
        m.w = (a.w * d.w == 0.f) ? MIN_D : 0.f;
        *(float4*)&amdmf[j] = m;
    }

    const int qloc = w * 16 + l15;
    const int qrow = row0 + qloc;
    bf16x8 qf[2];
    {
        const unsigned short* qp = q + ((size_t)(b * Ss + qrow)) * Dm + h * HDd + l4 * 8;
        qf[0] = *(const bf16x8*)qp;
        qf[1] = *(const bf16x8*)(qp + 32);
    }

    f32x4 acc[4];
#pragma unroll
    for (int d2 = 0; d2 < 4; ++d2) acc[d2] = (f32x4)(0.f);
    float mrun = -INFINITY, lrun = 0.f;
    const int ktmax = 2 * qt + 1;

    for (int kt = 0; kt <= ktmax; ++kt) {
        __syncthreads();
        {
            int key = tid >> 3, pc = tid & 7, lc = pc ^ (key & 7);
            uint4 vv = *(const uint4*)(k + ((size_t)(b * Ss + kt * 64 + key)) * Dm
                                       + h * HDd + lc * 8);
            *(uint4*)&Ksm[tid * 16] = vv;
        }
        {
            int d = tid >> 3, pc = tid & 7, lc = pc ^ (d & 7);
            uint4 vv = *(const uint4*)(vt + ((size_t)(b * Hh + h) * HDd + d) * Ss
                                       + kt * 64 + lc * 8);
            *(uint4*)&Vsm[tid * 16] = vv;
        }
        __syncthreads();

        f32x4 sreg[4];
#pragma unroll
        for (int kb = 0; kb < 4; ++kb) {
            const int key16 = kb * 16 + l15;
            const int sw = key16 & 7;
            bf16x8 k0 = *(bf16x8*)&Ksm[key16 * 128 + ((l4 ^ sw) * 16)];
            bf16x8 k1 = *(bf16x8*)&Ksm[key16 * 128 + (((4 + l4) ^ sw) * 16)];
            f32x4 s = (f32x4)(0.f);
            s = __builtin_amdgcn_mfma_f32_16x16x32_bf16(k0, qf[0], s, 0, 0, 0);
            s = __builtin_amdgcn_mfma_f32_16x16x32_bf16(k1, qf[1], s, 0, 0, 0);
            sreg[kb] = s;
        }

        float sv[16];
#pragma unroll
        for (int kb = 0; kb < 4; ++kb)
#pragma unroll
            for (int r = 0; r < 4; ++r) {
                const int key = kt * 64 + kb * 16 + l4 * 4 + r;
                const float mval = (key > qrow) ? MIN_D : amdmf[key];
                sv[kb * 4 + r] = fmaf(sreg[kb][r], C2, mval);
            }

        float pm = fmaxf(fmaxf(sv[0], sv[1]), sv[2]);
        pm = fmaxf(fmaxf(pm, sv[3]), fmaxf(sv[4], sv[5]));
        pm = fmaxf(fmaxf(pm, sv[6]), fmaxf(sv[7], sv[8]));
        pm = fmaxf(fmaxf(pm, sv[9]), fmaxf(sv[10], sv[11]));
        pm = fmaxf(fmaxf(pm, sv[12]), fmaxf(sv[13], sv[14]));
        pm = fmaxf(pm, sv[15]);
        pm = fmaxf(pm, __shfl_xor(pm, 16));
        pm = fmaxf(pm, __shfl_xor(pm, 32));

        if (__any(pm > mrun + 8.f)) {
            const float mn = fmaxf(mrun, pm);
            const float sc = __builtin_amdgcn_exp2f(mrun - mn);
            lrun *= sc;
#pragma unroll
            for (int d2 = 0; d2 < 4; ++d2) acc[d2] *= sc;
            mrun = mn;
        }

        float p[16], rs = 0.f;
#pragma unroll
        for (int i = 0; i < 16; ++i) {
            p[i] = __builtin_amdgcn_exp2f(sv[i] - mrun);
            rs += p[i];
        }
        rs += __shfl_xor(rs, 16);
        rs += __shfl_xor(rs, 32);
        lrun += rs;

        const unsigned pswz = (l15 & 7) << 4;
#pragma unroll
        for (int kb = 0; kb < 4; ++kb) {
            uint2 u;
            u.x = pk_bf16(p[kb * 4 + 0], p[kb * 4 + 1]);
            u.y = pk_bf16(p[kb * 4 + 2], p[kb * 4 + 3]);
            *(uint2*)&Psm[qloc * 128 + ((kb * 32 + l4 * 8) ^ pswz)] = u;
        }

#pragma unroll
        for (int ks = 0; ks < 2; ++ks) {
            bf16x8 pa = *(bf16x8*)&Psm[qloc * 128 + ((ks * 64 + l4 * 16) ^ pswz)];
#pragma unroll
            for (int d2 = 0; d2 < 4; ++d2) {
                const int dd = d2 * 16 + l15;
                bf16x8 vb = *(bf16x8*)&Vsm[dd * 128 + ((ks * 64 + l4 * 16) ^ ((dd & 7) << 4))];
                acc[d2] = __builtin_amdgcn_mfma_f32_16x16x32_bf16(vb, pa, acc[d2], 0, 0, 0);
            }
        }
    }

    const float inv = 1.f / lrun;
    const bool uni = (mrun <= -1e37f);
    __syncthreads();
    unsigned short* stg = (unsigned short*)smem;
    uniflag[qloc] = uni ? 1.f : 0.f;
#pragma unroll
    for (int d2 = 0; d2 < 4; ++d2) {
        uint2 u;
        u.x = pk_bf16(acc[d2][0] * inv, acc[d2][1] * inv);
        u.y = pk_bf16(acc[d2][2] * inv, acc[d2][3] * inv);
        *(uint2*)&stg[qloc * 72 + d2 * 16 + l4 * 4] = u;
    }
    __syncthreads();
    {
        const int r = tid >> 2, c16 = (tid & 3) * 16;
        const bool u = uniflag[r] != 0.f;
        uint4 o0, o1;
        if (u) {
            unsigned short ob[16];
#pragma unroll
            for (int i = 0; i < 16; ++i)
                ob[i] = f2bf(meanv[b * Dm + h * HDd + c16 + i]);
            o0 = *(uint4*)&ob[0];
            o1 = *(uint4*)&ob[8];
        } else {
            o0 = *(uint4*)&stg[r * 72 + c16];
            o1 = *(uint4*)&stg[r * 72 + c16 + 8];
        }
        unsigned short* op = o + ((size_t)(b * Ss + row0 + r)) * Dm + h * HDd + c16;
        *(uint4*)op = o0;
        *(uint4*)(op + 8) = o1;
    }
}

// ---------------------------------------------------------------------------
extern "C" void kernel_launch(void* const* d_in, const int* in_sizes, int n_in,
                              void* d_out, int out_size, void* d_ws, size_t ws_size,
                              hipStream_t stream)
{
    const float* hs     = (const float*)d_in[0];
    const float* amask  = (const float*)d_in[1];
    const float* Wq     = (const float*)d_in[2];
    const float* bq     = (const float*)d_in[3];
    const float* Wk     = (const float*)d_in[4];
    const float* bk     = (const float*)d_in[5];
    const float* dmask  = (const float*)d_in[6];
    const float* Wvq    = (const float*)d_in[7];
    const float* bvq    = (const float*)d_in[8];
    const float* vkeys  = (const float*)d_in[9];
    const float* vembed = (const float*)d_in[10];
    const float* Wo     = (const float*)d_in[11];
    const float* bo     = (const float*)d_in[12];
    float* out = (float*)d_out;

    char* w = (char*)d_ws;
    size_t off = 0;
    auto take = [&](size_t n) { char* p = w + off; off = (off + n + 255) & ~(size_t)255; return p; };
    unsigned short* hsbf  = (unsigned short*)take((size_t)Mrows * Dm * 2);
    unsigned short* WqT   = (unsigned short*)take((size_t)Dm * Dm * 2);
    unsigned short* WkT   = (unsigned short*)take((size_t)Dm * Dm * 2);
    unsigned short* WoT   = (unsigned short*)take((size_t)Dm * Dm * 2);
    unsigned short* qbf   = (unsigned short*)take((size_t)Mrows * Dm * 2);
    unsigned short* kbf   = (unsigned short*)take((size_t)Mrows * Dm * 2);
    unsigned short* vtb   = (unsigned short*)take((size_t)Mrows * Dm * 2);   // VT
    unsigned short* attno = (unsigned short*)take((size_t)Mrows * Dm * 2);
    float* vqp   = (float*)take((size_t)4 * Mrows * DRr * 4);               // split-K partials
    float* vqb   = (float*)take((size_t)Mrows * DRr * 4);
    unsigned short* vq_hi = (unsigned short*)take((size_t)Mrows * DRr * 2);
    unsigned short* vk_hi = (unsigned short*)take((size_t)NV * DRr * 2);
    float* rtm   = (float*)take((size_t)64 * Mrows * 4);                    // [tile][row]
    float* thr   = (float*)take((size_t)Mrows * 4);
    unsigned long long* best = (unsigned long long*)take((size_t)Mrows * 8);
    float* mvb   = (float*)take((size_t)Bb * Dm * 4);

    hipMemsetAsync(best, 0, (size_t)Mrows * 8, stream);

    dim3 blk(256);
    // dtype prep
    cvt_bf16<<<dim3(Mrows * Dm / 2048), blk, 0, stream>>>(hs, hsbf);
    transpose_cvt3<<<dim3(Dm / 64, Dm / 64, 3), blk, 0, stream>>>(Wq, Wk, Wo, WqT, WkT, WoT);
    // Q,K projections fused via z
    gemm_bf16<true><<<dim3(Dm / 128, Mrows / 128, 2), dim3(512), 0, stream>>>(
        hsbf, WqT, WkT, bq, bk, qbf, kbf, Dm, Dm);
    // retrieval: split-K exact vq, reduce(+bf16 copy), screen pass0, exact tiles
    gemm_vq_partial<<<dim3(DRr / 64, Mrows / 64, 4), blk, 0, stream>>>(hs, Wvq, vqp);
    reduce_vq<<<dim3(Mrows * DRr / 1024), blk, 0, stream>>>(vqp, bvq, vqb, vq_hi);
    cvt_bf16<<<dim3(NV * DRr / 2048), blk, 0, stream>>>(vkeys, vk_hi);
    sim_gemm0<<<dim3(NV / 128, Mrows / 128), dim3(512), 0, stream>>>(vq_hi, vk_hi, rtm);
    sim_combine2<<<dim3(Mrows / 256), blk, 0, stream>>>(rtm, thr);
    sim_exact<<<dim3(NV / 128), blk, 0, stream>>>(rtm, thr, vqb, vkeys, best);
    // fused build+transpose of V, then mean
    build_vt<<<dim3(Ss / 64, Bb * Hh), blk, 0, stream>>>(hs, vembed, best, vtb);
    mean_vt<<<dim3(Bb * Hh), blk, 0, stream>>>(vtb, mvb);
    // attention (512 threads)
    attn_mfma4<<<dim3(Ss / 128, Hh, Bb), dim3(512), 0, stream>>>(
        qbf, kbf, vtb, amask, dmask, mvb, attno);
    // output projection (f32 out)
    gemm_bf16<false><<<dim3(Dm / 128, Mrows / 128, 1), dim3(512), 0, stream>>>(
        attno, WoT, WoT, bo, bo, out, out, Dm, Dm);
}

// Round 13
// 292.732 us; speedup vs baseline: 11.2065x; 1.3301x over previous
//
#include <hip/hip_runtime.h>
#include <hip/hip_bf16.h>
#include <math.h>

#define MIN_D (-3.402823466e+38f)

constexpr int Bb = 2, Ss = 2048, Dm = 1024, Hh = 16, HDd = 64, NV = 8192, DRr = 128;
constexpr int Mrows = Bb * Ss;   // 4096
constexpr float MARGIN = 0.01f;  // >> 2x bf16-MFMA sim error (~1e-3 RSS)
constexpr int CAP = 262144;      // (row,tile) pair buffer — cannot overflow (64*4096)
constexpr float C2 = 0.18033688011112042f;   // 0.125 * log2(e)

typedef __attribute__((ext_vector_type(8))) short bf16x8;
typedef __attribute__((ext_vector_type(4))) float f32x4;

__device__ inline unsigned short f2bf(float x) {
    union { float f; unsigned u; } v; v.f = x;
    unsigned r = v.u + 0x7fff + ((v.u >> 16) & 1);   // RNE
    return (unsigned short)(r >> 16);
}
__device__ inline float bf2f(unsigned short u) {
    union { unsigned u; float f; } v; v.u = ((unsigned)u) << 16;
    return v.f;
}
__device__ inline unsigned pk_bf16(float a, float b) {   // native cvt_pk
    float2 t; t.x = a; t.y = b;
    __hip_bfloat162 h = __float22bfloat162_rn(t);
    return *(unsigned*)&h;
}

// ---------------------------------------------------------------------------
// f32 -> bf16 elementwise. 8 elems/thread; grid = n/2048.
// ---------------------------------------------------------------------------
__global__ __launch_bounds__(256)
void cvt_bf16(const float* __restrict__ x, unsigned short* __restrict__ y)
{
    size_t i = ((size_t)blockIdx.x * 256 + threadIdx.x) * 8;
    float4 a = *(const float4*)(x + i);
    float4 b = *(const float4*)(x + i + 4);
    uint4 p;
    p.x = pk_bf16(a.x, a.y);
    p.y = pk_bf16(a.z, a.w);
    p.z = pk_bf16(b.x, b.y);
    p.w = pk_bf16(b.z, b.w);
    *(uint4*)(y + i) = p;
}

// ---------------------------------------------------------------------------
// Fused transpose+convert of the three 1024x1024 weights (z selects).
// ---------------------------------------------------------------------------
__global__ __launch_bounds__(256)
void transpose_cvt3(const float* __restrict__ W0, const float* __restrict__ W1,
                    const float* __restrict__ W2, unsigned short* __restrict__ T0,
                    unsigned short* __restrict__ T1, unsigned short* __restrict__ T2)
{
    const float* W = blockIdx.z == 0 ? W0 : (blockIdx.z == 1 ? W1 : W2);
    unsigned short* WT = blockIdx.z == 0 ? T0 : (blockIdx.z == 1 ? T1 : T2);
    __shared__ unsigned short T[64][72];
    const int tid = threadIdx.x;
    const int n0 = blockIdx.x * 64, k0 = blockIdx.y * 64;
    const int rr = tid >> 4, cc = tid & 15;
#pragma unroll
    for (int q2 = 0; q2 < 4; ++q2) {
        int kk = rr * 4 + q2;
        float4 v = *(const float4*)(W + (size_t)(k0 + kk) * Dm + n0 + cc * 4);
        T[cc * 4 + 0][kk] = f2bf(v.x);
        T[cc * 4 + 1][kk] = f2bf(v.y);
        T[cc * 4 + 2][kk] = f2bf(v.z);
        T[cc * 4 + 3][kk] = f2bf(v.w);
    }
    __syncthreads();
#pragma unroll
    for (int q2 = 0; q2 < 4; ++q2) {
        int nn = rr * 4 + q2;
        uint2 u;
        u.x = (unsigned)T[nn][cc * 4 + 0] | ((unsigned)T[nn][cc * 4 + 1] << 16);
        u.y = (unsigned)T[nn][cc * 4 + 2] | ((unsigned)T[nn][cc * 4 + 3] << 16);
        *(uint2*)(WT + (size_t)(n0 + nn) * Dm + k0 + cc * 4) = u;
    }
}

// ---------------------------------------------------------------------------
// bf16 MFMA GEMM, 128x128 tile, 512 thr = 8 waves (2m x 4n), BK=32.
// Dual-target via blockIdx.z. (Unchanged, proven.)
// ---------------------------------------------------------------------------
template<bool BF16OUT>
__global__ __launch_bounds__(512)
void gemm_bf16(const unsigned short* __restrict__ A,
               const unsigned short* BT0, const unsigned short* BT1,
               const float* bias0, const float* bias1,
               void* C0, void* C1, int N, int K)
{
    const unsigned short* BT = blockIdx.z ? BT1 : BT0;
    const float* bias = blockIdx.z ? bias1 : bias0;
    void* C = blockIdx.z ? C1 : C0;
    __shared__ __align__(16) unsigned short As[128 * 32];
    __shared__ __align__(16) unsigned short Bs[128 * 32];
    const int tid = threadIdx.x;
    const int l = tid & 63, w = tid >> 6;
    const int l15 = l & 15, l4 = l >> 4;
    const int wm = w >> 2, wn = w & 3;           // 2 x 4 wave grid
    const int row0 = blockIdx.y * 128, col0 = blockIdx.x * 128;

    f32x4 acc[4][2];
#pragma unroll
    for (int mi = 0; mi < 4; ++mi)
#pragma unroll
        for (int ni = 0; ni < 2; ++ni) acc[mi][ni] = (f32x4)(0.f);

    for (int k0 = 0; k0 < K; k0 += 32) {
        __syncthreads();
        {
            int r = tid >> 2, pc = tid & 3;
            uint4 vv = *(const uint4*)(A + (size_t)(row0 + r) * K + k0 + pc * 8);
            *(uint4*)&As[tid * 8] = vv;
        }
        {
            int r = tid >> 2, pc = tid & 3;
            uint4 vv = *(const uint4*)(BT + (size_t)(col0 + r) * K + k0 + pc * 8);
            *(uint4*)&Bs[tid * 8] = vv;
        }
        __syncthreads();

        bf16x8 af[4], bf[2];
#pragma unroll
        for (int mi = 0; mi < 4; ++mi)
            af[mi] = *(bf16x8*)&As[(wm * 64 + mi * 16 + l15) * 32 + l4 * 8];
#pragma unroll
        for (int ni = 0; ni < 2; ++ni)
            bf[ni] = *(bf16x8*)&Bs[(wn * 32 + ni * 16 + l15) * 32 + l4 * 8];
#pragma unroll
        for (int mi = 0; mi < 4; ++mi)
#pragma unroll
            for (int ni = 0; ni < 2; ++ni)
                acc[mi][ni] = __builtin_amdgcn_mfma_f32_16x16x32_bf16(af[mi], bf[ni], acc[mi][ni], 0, 0, 0);
    }

#pragma unroll
    for (int mi = 0; mi < 4; ++mi)
#pragma unroll
        for (int ni = 0; ni < 2; ++ni)
#pragma unroll
            for (int j = 0; j < 4; ++j) {
                int row = row0 + wm * 64 + mi * 16 + l4 * 4 + j;
                int col = col0 + wn * 32 + ni * 16 + l15;
                float vv = acc[mi][ni][j] + bias[col];
                if (BF16OUT)
                    ((unsigned short*)C)[(size_t)row * N + col] = f2bf(vv);
                else
                    ((float*)C)[(size_t)row * N + col] = vv;
            }
}

// ---------------------------------------------------------------------------
// Split-K f32 GEMM for vq: partial[z] = A[:, z*256:(z+1)*256] @ W-slice.
// ---------------------------------------------------------------------------
__global__ __launch_bounds__(256)
void gemm_vq_partial(const float* __restrict__ A, const float* __restrict__ W,
                     float* __restrict__ P)
{
    __shared__ float As[64][36];
    __shared__ float Ws[32][64];
    const int tid = threadIdx.x;
    const int row0 = blockIdx.y * 64, col0 = blockIdx.x * 64;
    const int kbase = blockIdx.z * 256;
    const int tr = tid >> 4, tc = tid & 15;
    float acc[4][4] = {};

    for (int k0 = kbase; k0 < kbase + 256; k0 += 32) {
        __syncthreads();
#pragma unroll
        for (int q2 = 0; q2 < 2; ++q2) {
            int oc = q2 * 256 + tid;
            int r = oc >> 3, c4 = (oc & 7) << 2;
            *(float4*)&As[r][c4] = *(const float4*)(A + (size_t)(row0 + r) * Dm + k0 + c4);
        }
#pragma unroll
        for (int q2 = 0; q2 < 2; ++q2) {
            int oc = q2 * 256 + tid;
            int r = oc >> 4, c4 = (oc & 15) << 2;
            *(float4*)&Ws[r][c4] = *(const float4*)(W + (size_t)(k0 + r) * DRr + col0 + c4);
        }
        __syncthreads();
#pragma unroll 8
        for (int kk = 0; kk < 32; ++kk) {
            float a[4];
#pragma unroll
            for (int i = 0; i < 4; ++i) a[i] = As[tr * 4 + i][kk];
            float4 bv = *(const float4*)&Ws[kk][tc * 4];
            float b[4] = {bv.x, bv.y, bv.z, bv.w};
#pragma unroll
            for (int i = 0; i < 4; ++i)
#pragma unroll
                for (int j = 0; j < 4; ++j)
                    acc[i][j] = fmaf(a[i], b[j], acc[i][j]);
        }
    }
    float* Pz = P + (size_t)blockIdx.z * Mrows * DRr;
#pragma unroll
    for (int i = 0; i < 4; ++i) {
        int r = row0 + tr * 4 + i;
        float4 ov = {acc[i][0], acc[i][1], acc[i][2], acc[i][3]};
        *(float4*)(Pz + (size_t)r * DRr + col0 + tc * 4) = ov;
    }
}

// ---------------------------------------------------------------------------
// Reduce split-K partials (fixed order) + bias -> vqb f32 and vq_hi bf16.
// ---------------------------------------------------------------------------
__global__ __launch_bounds__(256)
void reduce_vq(const float* __restrict__ P, const float* __restrict__ bias,
               float* __restrict__ vqb, unsigned short* __restrict__ vq_hi)
{
    const size_t i4 = ((size_t)blockIdx.x * 256 + threadIdx.x) * 4;
    const int col = (int)(i4 & 127);
    const size_t stride = (size_t)Mrows * DRr;
    float4 s = *(const float4*)(P + i4);
#pragma unroll
    for (int z = 1; z < 4; ++z) {
        float4 p = *(const float4*)(P + stride * z + i4);
        s.x += p.x; s.y += p.y; s.z += p.z; s.w += p.w;
    }
    float4 bv = *(const float4*)(bias + col);
    s.x += bv.x; s.y += bv.y; s.z += bv.z; s.w += bv.w;
    *(float4*)(vqb + i4) = s;
    uint2 u;
    u.x = pk_bf16(s.x, s.y);
    u.y = pk_bf16(s.z, s.w);
    *(uint2*)(vq_hi + i4) = u;
}

// ---------------------------------------------------------------------------
// Screen pass 0 (R10-proven GEMM structure + global_load_lds staging):
// per-(row, 128-key tile) bf16 maxima -> rtm[tile][row] (transposed layout).
// ---------------------------------------------------------------------------
__global__ __launch_bounds__(512)
void sim_gemm0(const unsigned short* __restrict__ A,
               const unsigned short* __restrict__ BT,
               float* __restrict__ rtm)
{
    __shared__ __align__(16) unsigned short As[128 * 32];
    __shared__ __align__(16) unsigned short Bs[128 * 32];
    __shared__ float red[128][4];
    const int tid = threadIdx.x;
    const int l = tid & 63, w = tid >> 6;
    const int l15 = l & 15, l4 = l >> 4;
    const int wm = w >> 2, wn = w & 3;
    const int row0 = blockIdx.y * 128, col0 = blockIdx.x * 128;

    f32x4 acc[4][2];
#pragma unroll
    for (int mi = 0; mi < 4; ++mi)
#pragma unroll
        for (int ni = 0; ni < 2; ++ni) acc[mi][ni] = (f32x4)(0.f);

    for (int k0 = 0; k0 < DRr; k0 += 32) {
        __syncthreads();
        {   // async global->LDS staging (m97 pattern; dest = base + lane*16)
            int r = tid >> 2, pc = tid & 3;
            __builtin_amdgcn_global_load_lds(
                (const __attribute__((address_space(1))) unsigned int*)(A + (size_t)(row0 + r) * DRr + k0 + pc * 8),
                (__attribute__((address_space(3))) unsigned int*)&As[tid * 8], 16, 0, 0);
            __builtin_amdgcn_global_load_lds(
                (const __attribute__((address_space(1))) unsigned int*)(BT + (size_t)(col0 + r) * DRr + k0 + pc * 8),
                (__attribute__((address_space(3))) unsigned int*)&Bs[tid * 8], 16, 0, 0);
        }
        __syncthreads();

        bf16x8 af[4], bf[2];
#pragma unroll
        for (int mi = 0; mi < 4; ++mi)
            af[mi] = *(bf16x8*)&As[(wm * 64 + mi * 16 + l15) * 32 + l4 * 8];
#pragma unroll
        for (int ni = 0; ni < 2; ++ni)
            bf[ni] = *(bf16x8*)&Bs[(wn * 32 + ni * 16 + l15) * 32 + l4 * 8];
#pragma unroll
        for (int mi = 0; mi < 4; ++mi)
#pragma unroll
            for (int ni = 0; ni < 2; ++ni)
                acc[mi][ni] = __builtin_amdgcn_mfma_f32_16x16x32_bf16(af[mi], bf[ni], acc[mi][ni], 0, 0, 0);
    }

    // per-row maxima over this block's 128 cols
    float rm[4][4];
#pragma unroll
    for (int mi = 0; mi < 4; ++mi)
#pragma unroll
        for (int j = 0; j < 4; ++j)
            rm[mi][j] = fmaxf(acc[mi][0][j], acc[mi][1][j]);
#pragma unroll
    for (int off = 1; off < 16; off <<= 1)
#pragma unroll
        for (int mi = 0; mi < 4; ++mi)
#pragma unroll
            for (int j = 0; j < 4; ++j)
                rm[mi][j] = fmaxf(rm[mi][j], __shfl_xor(rm[mi][j], off));
    if (l15 == 0) {
#pragma unroll
        for (int mi = 0; mi < 4; ++mi)
#pragma unroll
            for (int j = 0; j < 4; ++j)
                red[wm * 64 + mi * 16 + l4 * 4 + j][wn] = rm[mi][j];
    }
    __syncthreads();
    if (tid < 128) {
        float m = fmaxf(fmaxf(red[tid][0], red[tid][1]),
                        fmaxf(red[tid][2], red[tid][3]));
        rtm[(size_t)blockIdx.x * Mrows + row0 + tid] = m;
    }
}

// ---------------------------------------------------------------------------
// thr[row] = max over 64 tile-maxima - MARGIN (rtm transposed: [tile][row]).
// ---------------------------------------------------------------------------
__global__ __launch_bounds__(256)
void sim_combine2(const float* __restrict__ rtm, float* __restrict__ thr)
{
    int r = blockIdx.x * 256 + threadIdx.x;
    if (r >= Mrows) return;
    float m = -INFINITY;
#pragma unroll 8
    for (int c = 0; c < 64; ++c)
        m = fmaxf(m, rtm[(size_t)c * Mrows + r]);
    thr[r] = m - MARGIN;
}

// ---------------------------------------------------------------------------
// Collect qualifying (row,tile) pairs. One thread per rtm entry (262144);
// ballot-aggregated pushes (~4300 selected -> ~1 atomic per nonempty wave).
// enc = row << 6 | tile.
// ---------------------------------------------------------------------------
__global__ __launch_bounds__(256)
void collect_pairs(const float* __restrict__ rtm, const float* __restrict__ thr,
                   unsigned* __restrict__ cnt, unsigned* __restrict__ pairs)
{
    const int idx = blockIdx.x * 256 + threadIdx.x;
    const int tile = idx >> 12, row = idx & 4095;
    const bool pred = rtm[(size_t)tile * Mrows + row] >= thr[row];
    unsigned long long mask = __ballot(pred);
    if (mask) {
        const int lane = threadIdx.x & 63;
        const int leader = __ffsll((long long)mask) - 1;
        unsigned base = 0;
        if (lane == leader) base = atomicAdd(cnt, (unsigned)__popcll(mask));
        base = (unsigned)__shfl((int)base, leader);
        if (pred) {
            unsigned off = (unsigned)__popcll(mask & ((1ull << lane) - 1ull));
            pairs[base + off] = ((unsigned)row << 6) | (unsigned)tile;
        }
    }
}

// ---------------------------------------------------------------------------
// Exact f32 rescore, one block per (row,tile) pair (grid-stride).
// Stage vq row (512B) in LDS; 256 thr = (key k, dim-half h); per-block
// argmax (shuffle, first-index tie-break); combine via u64 atomicMax.
// Same enc/reduction as R12 -> identical indices.
// ---------------------------------------------------------------------------
__global__ __launch_bounds__(256)
void rescore_pair(const unsigned* __restrict__ pairs, const unsigned* __restrict__ cnt,
                  const float* __restrict__ vq, const float* __restrict__ vkeys,
                  unsigned long long* __restrict__ best)
{
    __shared__ float vqs[128];
    __shared__ float part[256];
    const int tid = threadIdx.x;
    const unsigned n = min(*cnt, (unsigned)CAP);
    for (unsigned i = blockIdx.x; i < n; i += gridDim.x) {
        const unsigned p = pairs[i];
        const unsigned row = p >> 6, tile = p & 63u;
        if (tid < 32) {
            float4 v = *(const float4*)(vq + (size_t)row * 128 + tid * 4);
            *(float4*)&vqs[tid * 4] = v;
        }
        __syncthreads();
        const int k = tid & 127, h = (tid >> 7) * 64;
        const float* kp = vkeys + (size_t)(tile * 128 + k) * 128 + h;
        float s = 0.f;
#pragma unroll
        for (int d = 0; d < 64; d += 4) {
            float4 kv = *(const float4*)(kp + d);
            s = fmaf(vqs[h + d + 0], kv.x, s);
            s = fmaf(vqs[h + d + 1], kv.y, s);
            s = fmaf(vqs[h + d + 2], kv.z, s);
            s = fmaf(vqs[h + d + 3], kv.w, s);
        }
        part[tid] = s;
        __syncthreads();
        if (tid < 64) {
            float s0 = part[tid] + part[tid + 128];
            float s1 = part[tid + 64] + part[tid + 192];
            float bs = s0; int bk = tid;
            if (s1 > s0) { bs = s1; bk = tid + 64; }
#pragma unroll
            for (int off = 1; off < 64; off <<= 1) {
                float os = __shfl_xor(bs, off);
                int ok = __shfl_xor(bk, off);
                if (os > bs || (os == bs && ok < bk)) { bs = os; bk = ok; }
            }
            if (tid == 0) {
                unsigned key = tile * 128 + bk;
                unsigned fb = __float_as_uint(bs);
                fb = (fb & 0x80000000u) ? ~fb : (fb | 0x80000000u);
                unsigned long long enc = ((unsigned long long)fb << 32) | (unsigned)(~key);
                atomicMax(best + row, enc);
            }
        }
        __syncthreads();   // vqs reuse guard for next pair
    }
}

// ---------------------------------------------------------------------------
// Fused build + transpose: VT[(b*16+h)*64 + d][key] = bf16(hs * vembed[idx]).
// ---------------------------------------------------------------------------
__global__ __launch_bounds__(256)
void build_vt(const float* __restrict__ hs, const float* __restrict__ vembed,
              const unsigned long long* __restrict__ best,
              unsigned short* __restrict__ vt)
{
    __shared__ unsigned short T[64][73];
    __shared__ int ids[64];
    const int tid = threadIdx.x;
    const int kt = blockIdx.x;
    const int bh = blockIdx.y;
    const int b = bh >> 4, h = bh & 15;
    if (tid < 64) {
        int row = b * Ss + kt * 64 + tid;
        ids[tid] = (int)((~(unsigned)(best[row] & 0xFFFFFFFFull)) & 8191u);
    }
    __syncthreads();
    {
        int r = tid >> 2, c16 = (tid & 3) * 16;
        size_t hrow = (size_t)(b * Ss + kt * 64 + r) * Dm + h * HDd + c16;
        size_t erow = (size_t)ids[r] * Dm + h * HDd + c16;
#pragma unroll
        for (int q2 = 0; q2 < 4; ++q2) {
            float4 a = *(const float4*)(hs + hrow + q2 * 4);
            float4 e = *(const float4*)(vembed + erow + q2 * 4);
            T[r][c16 + q2 * 4 + 0] = f2bf(a.x * e.x);
            T[r][c16 + q2 * 4 + 1] = f2bf(a.y * e.y);
            T[r][c16 + q2 * 4 + 2] = f2bf(a.z * e.z);
            T[r][c16 + q2 * 4 + 3] = f2bf(a.w * e.w);
        }
    }
    __syncthreads();
    {
        int d = tid >> 2, kc = (tid & 3) * 16;
        unsigned short ob[16];
#pragma unroll
        for (int i = 0; i < 16; ++i) ob[i] = T[kc + i][d];
        unsigned short* op = vt + ((size_t)(b * Hh + h) * HDd + d) * Ss + kt * 64 + kc;
        *(uint4*)op = *(uint4*)&ob[0];
        *(uint4*)(op + 8) = *(uint4*)&ob[8];
    }
}

// ---------------------------------------------------------------------------
// meanv[b][h*64+d] from VT row sums (fully-masked-row substitution value).
// ---------------------------------------------------------------------------
__global__ __launch_bounds__(256)
void mean_vt(const unsigned short* __restrict__ vt, float* __restrict__ mv)
{
    const int bh = blockIdx.x;
    const int b = bh >> 4, h = bh & 15;
    const int d = threadIdx.x >> 2, part = threadIdx.x & 3;
    const unsigned short* row = vt + ((size_t)bh * HDd + d) * Ss + part * 512;
    float s = 0.f;
    for (int j = 0; j < 512; j += 8) {
        uint4 u = *(const uint4*)(row + j);
        const unsigned uu[4] = {u.x, u.y, u.z, u.w};
#pragma unroll
        for (int m = 0; m < 4; ++m) {
            s += bf2f((unsigned short)(uu[m] & 0xffff));
            s += bf2f((unsigned short)(uu[m] >> 16));
        }
    }
    s += __shfl_xor(s, 1);
    s += __shfl_xor(s, 2);
    if (part == 0) mv[b * Dm + h * HDd + d] = s * (1.f / 2048.f);
}

// ---------------------------------------------------------------------------
// bf16 MFMA flash attention v4 (unchanged): QBLK=128/8 waves, swapped QK^T,
// pre-transposed V, log2 softmax + defer-rescale, balanced qt pairing.
// ---------------------------------------------------------------------------
__global__ __launch_bounds__(512)
void attn_mfma4(const unsigned short* __restrict__ q, const unsigned short* __restrict__ k,
                const unsigned short* __restrict__ vt, const float* __restrict__ am,
                const float* __restrict__ dmask, const float* __restrict__ meanv,
                unsigned short* __restrict__ o)
{
    __shared__ __align__(16) unsigned char smem[40960]; // K 8K | VT 8K | P 16K | amdm 8K
    __shared__ float uniflag[128];
    unsigned char* Ksm = smem;
    unsigned char* Vsm = smem + 8192;
    unsigned char* Psm = smem + 16384;
    float* amdmf = (float*)(smem + 32768);

    const int tid = threadIdx.x;
    const int l = tid & 63, w = tid >> 6;
    const int l15 = l & 15, l4 = l >> 4;
    const int lin = blockIdx.x + (blockIdx.y << 4) + (blockIdx.z << 8);
    const int half = lin >> 8, rem = lin & 255;
    const int qtb = rem & 15;
    const int qt = half ? (15 - qtb) : qtb;
    const int h = rem >> 4;
    const int b = half;
    const int row0 = qt * 128;

    {
        int j = tid * 4;
        float4 a = *(const float4*)(am + b * Ss + j);
        float4 d = *(const float4*)(dmask + h * Ss + j);
        float4 m;
        m.x = (a.x * d.x == 0.f) ? MIN_D : 0.f;
        m.y = (a.y * d.y == 0.f) ? MIN_D : 0.f;
        m.z = (a.z * d.z == 0.f) ? MIN_D : 0.f;
        m.w = (a.w * d.w == 0.f) ? MIN_D : 0.f;
        *(float4*)&amdmf[j] = m;
    }

    const int qloc = w * 16 + l15;
    const int qrow = row0 + qloc;
    bf16x8 qf[2];
    {
        const unsigned short* qp = q + ((size_t)(b * Ss + qrow)) * Dm + h * HDd + l4 * 8;
        qf[0] = *(const bf16x8*)qp;
        qf[1] = *(const bf16x8*)(qp + 32);
    }

    f32x4 acc[4];
#pragma unroll
    for (int d2 = 0; d2 < 4; ++d2) acc[d2] = (f32x4)(0.f);
    float mrun = -INFINITY, lrun = 0.f;
    const int ktmax = 2 * qt + 1;

    for (int kt = 0; kt <= ktmax; ++kt) {
        __syncthreads();
        {
            int key = tid >> 3, pc = tid & 7, lc = pc ^ (key & 7);
            uint4 vv = *(const uint4*)(k + ((size_t)(b * Ss + kt * 64 + key)) * Dm
                                       + h * HDd + lc * 8);
            *(uint4*)&Ksm[tid * 16] = vv;
        }
        {
            int d = tid >> 3, pc = tid & 7, lc = pc ^ (d & 7);
            uint4 vv = *(const uint4*)(vt + ((size_t)(b * Hh + h) * HDd + d) * Ss
                                       + kt * 64 + lc * 8);
            *(uint4*)&Vsm[tid * 16] = vv;
        }
        __syncthreads();

        f32x4 sreg[4];
#pragma unroll
        for (int kb = 0; kb < 4; ++kb) {
            const int key16 = kb * 16 + l15;
            const int sw = key16 & 7;
            bf16x8 k0 = *(bf16x8*)&Ksm[key16 * 128 + ((l4 ^ sw) * 16)];
            bf16x8 k1 = *(bf16x8*)&Ksm[key16 * 128 + (((4 + l4) ^ sw) * 16)];
            f32x4 s = (f32x4)(0.f);
            s = __builtin_amdgcn_mfma_f32_16x16x32_bf16(k0, qf[0], s, 0, 0, 0);
            s = __builtin_amdgcn_mfma_f32_16x16x32_bf16(k1, qf[1], s, 0, 0, 0);
            sreg[kb] = s;
        }

        float sv[16];
#pragma unroll
        for (int kb = 0; kb < 4; ++kb)
#pragma unroll
            for (int r = 0; r < 4; ++r) {
                const int key = kt * 64 + kb * 16 + l4 * 4 + r;
                const float mval = (key > qrow) ? MIN_D : amdmf[key];
                sv[kb * 4 + r] = fmaf(sreg[kb][r], C2, mval);
            }

        float pm = fmaxf(fmaxf(sv[0], sv[1]), sv[2]);
        pm = fmaxf(fmaxf(pm, sv[3]), fmaxf(sv[4], sv[5]));
        pm = fmaxf(fmaxf(pm, sv[6]), fmaxf(sv[7], sv[8]));
        pm = fmaxf(fmaxf(pm, sv[9]), fmaxf(sv[10], sv[11]));
        pm = fmaxf(fmaxf(pm, sv[12]), fmaxf(sv[13], sv[14]));
        pm = fmaxf(pm, sv[15]);
        pm = fmaxf(pm, __shfl_xor(pm, 16));
        pm = fmaxf(pm, __shfl_xor(pm, 32));

        if (__any(pm > mrun + 8.f)) {
            const float mn = fmaxf(mrun, pm);
            const float sc = __builtin_amdgcn_exp2f(mrun - mn);
            lrun *= sc;
#pragma unroll
            for (int d2 = 0; d2 < 4; ++d2) acc[d2] *= sc;
            mrun = mn;
        }

        float p[16], rs = 0.f;
#pragma unroll
        for (int i = 0; i < 16; ++i) {
            p[i] = __builtin_amdgcn_exp2f(sv[i] - mrun);
            rs += p[i];
        }
        rs += __shfl_xor(rs, 16);
        rs += __shfl_xor(rs, 32);
        lrun += rs;

        const unsigned pswz = (l15 & 7) << 4;
#pragma unroll
        for (int kb = 0; kb < 4; ++kb) {
            uint2 u;
            u.x = pk_bf16(p[kb * 4 + 0], p[kb * 4 + 1]);
            u.y = pk_bf16(p[kb * 4 + 2], p[kb * 4 + 3]);
            *(uint2*)&Psm[qloc * 128 + ((kb * 32 + l4 * 8) ^ pswz)] = u;
        }

#pragma unroll
        for (int ks = 0; ks < 2; ++ks) {
            bf16x8 pa = *(bf16x8*)&Psm[qloc * 128 + ((ks * 64 + l4 * 16) ^ pswz)];
#pragma unroll
            for (int d2 = 0; d2 < 4; ++d2) {
                const int dd = d2 * 16 + l15;
                bf16x8 vb = *(bf16x8*)&Vsm[dd * 128 + ((ks * 64 + l4 * 16) ^ ((dd & 7) << 4))];
                acc[d2] = __builtin_amdgcn_mfma_f32_16x16x32_bf16(vb, pa, acc[d2], 0, 0, 0);
            }
        }
    }

    const float inv = 1.f / lrun;
    const bool uni = (mrun <= -1e37f);
    __syncthreads();
    unsigned short* stg = (unsigned short*)smem;
    uniflag[qloc] = uni ? 1.f : 0.f;
#pragma unroll
    for (int d2 = 0; d2 < 4; ++d2) {
        uint2 u;
        u.x = pk_bf16(acc[d2][0] * inv, acc[d2][1] * inv);
        u.y = pk_bf16(acc[d2][2] * inv, acc[d2][3] * inv);
        *(uint2*)&stg[qloc * 72 + d2 * 16 + l4 * 4] = u;
    }
    __syncthreads();
    {
        const int r = tid >> 2, c16 = (tid & 3) * 16;
        const bool u = uniflag[r] != 0.f;
        uint4 o0, o1;
        if (u) {
            unsigned short ob[16];
#pragma unroll
            for (int i = 0; i < 16; ++i)
                ob[i] = f2bf(meanv[b * Dm + h * HDd + c16 + i]);
            o0 = *(uint4*)&ob[0];
            o1 = *(uint4*)&ob[8];
        } else {
            o0 = *(uint4*)&stg[r * 72 + c16];
            o1 = *(uint4*)&stg[r * 72 + c16 + 8];
        }
        unsigned short* op = o + ((size_t)(b * Ss + row0 + r)) * Dm + h * HDd + c16;
        *(uint4*)op = o0;
        *(uint4*)(op + 8) = o1;
    }
}

// ---------------------------------------------------------------------------
extern "C" void kernel_launch(void* const* d_in, const int* in_sizes, int n_in,
                              void* d_out, int out_size, void* d_ws, size_t ws_size,
                              hipStream_t stream)
{
    const float* hs     = (const float*)d_in[0];
    const float* amask  = (const float*)d_in[1];
    const float* Wq     = (const float*)d_in[2];
    const float* bq     = (const float*)d_in[3];
    const float* Wk     = (const float*)d_in[4];
    const float* bk     = (const float*)d_in[5];
    const float* dmask  = (const float*)d_in[6];
    const float* Wvq    = (const float*)d_in[7];
    const float* bvq    = (const float*)d_in[8];
    const float* vkeys  = (const float*)d_in[9];
    const float* vembed = (const float*)d_in[10];
    const float* Wo     = (const float*)d_in[11];
    const float* bo     = (const float*)d_in[12];
    float* out = (float*)d_out;

    char* w = (char*)d_ws;
    size_t off = 0;
    auto take = [&](size_t n) { char* p = w + off; off = (off + n + 255) & ~(size_t)255; return p; };
    unsigned short* hsbf  = (unsigned short*)take((size_t)Mrows * Dm * 2);
    unsigned short* WqT   = (unsigned short*)take((size_t)Dm * Dm * 2);
    unsigned short* WkT   = (unsigned short*)take((size_t)Dm * Dm * 2);
    unsigned short* WoT   = (unsigned short*)take((size_t)Dm * Dm * 2);
    unsigned short* qbf   = (unsigned short*)take((size_t)Mrows * Dm * 2);
    unsigned short* kbf   = (unsigned short*)take((size_t)Mrows * Dm * 2);
    unsigned short* vtb   = (unsigned short*)take((size_t)Mrows * Dm * 2);   // VT
    unsigned short* attno = (unsigned short*)take((size_t)Mrows * Dm * 2);
    float* vqp   = (float*)take((size_t)4 * Mrows * DRr * 4);               // split-K partials
    float* vqb   = (float*)take((size_t)Mrows * DRr * 4);
    unsigned short* vq_hi = (unsigned short*)take((size_t)Mrows * DRr * 2);
    unsigned short* vk_hi = (unsigned short*)take((size_t)NV * DRr * 2);
    float* rtm   = (float*)take((size_t)64 * Mrows * 4);                    // [tile][row]
    float* thr   = (float*)take((size_t)Mrows * 4);
    unsigned* cnt = (unsigned*)take(256);
    unsigned* pairs = (unsigned*)take((size_t)CAP * 4);
    unsigned long long* best = (unsigned long long*)take((size_t)Mrows * 8);
    float* mvb   = (float*)take((size_t)Bb * Dm * 4);

    hipMemsetAsync(cnt, 0, 4, stream);
    hipMemsetAsync(best, 0, (size_t)Mrows * 8, stream);

    dim3 blk(256);
    // dtype prep
    cvt_bf16<<<dim3(Mrows * Dm / 2048), blk, 0, stream>>>(hs, hsbf);
    transpose_cvt3<<<dim3(Dm / 64, Dm / 64, 3), blk, 0, stream>>>(Wq, Wk, Wo, WqT, WkT, WoT);
    // Q,K projections fused via z
    gemm_bf16<true><<<dim3(Dm / 128, Mrows / 128, 2), dim3(512), 0, stream>>>(
        hsbf, WqT, WkT, bq, bk, qbf, kbf, Dm, Dm);
    // retrieval: split-K exact vq, reduce(+bf16 copy), screen pass0,
    // pair collection, exact per-pair rescore
    gemm_vq_partial<<<dim3(DRr / 64, Mrows / 64, 4), blk, 0, stream>>>(hs, Wvq, vqp);
    reduce_vq<<<dim3(Mrows * DRr / 1024), blk, 0, stream>>>(vqp, bvq, vqb, vq_hi);
    cvt_bf16<<<dim3(NV * DRr / 2048), blk, 0, stream>>>(vkeys, vk_hi);
    sim_gemm0<<<dim3(NV / 128, Mrows / 128), dim3(512), 0, stream>>>(vq_hi, vk_hi, rtm);
    sim_combine2<<<dim3(Mrows / 256), blk, 0, stream>>>(rtm, thr);
    collect_pairs<<<dim3(64 * Mrows / 256), blk, 0, stream>>>(rtm, thr, cnt, pairs);
    rescore_pair<<<dim3(2048), blk, 0, stream>>>(pairs, cnt, vqb, vkeys, best);
    // fused build+transpose of V, then mean
    build_vt<<<dim3(Ss / 64, Bb * Hh), blk, 0, stream>>>(hs, vembed, best, vtb);
    mean_vt<<<dim3(Bb * Hh), blk, 0, stream>>>(vtb, mvb);
    // attention (512 threads)
    attn_mfma4<<<dim3(Ss / 128, Hh, Bb), dim3(512), 0, stream>>>(
        qbf, kbf, vtb, amask, dmask, mvb, attno);
    // output projection (f32 out)
    gemm_bf16<false><<<dim3(Dm / 128, Mrows / 128, 1), dim3(512), 0, stream>>>(
        attno, WoT, WoT, bo, bo, out, out, Dm, Dm);
}

// Round 15
// 276.492 us; speedup vs baseline: 11.8647x; 1.0587x over previous
//
#include <hip/hip_runtime.h>
#include <hip/hip_bf16.h>
#include <math.h>

#define MIN_D (-3.402823466e+38f)

constexpr int Bb = 2, Ss = 2048, Dm = 1024, Hh = 16, HDd = 64, NV = 8192, DRr = 128;
constexpr int Mrows = Bb * Ss;   // 4096
constexpr float MARGIN = 0.01f;  // >> 2x bf16-MFMA sim error (~1e-3 RSS)
constexpr int CAP = 262144;      // (row,tile) pair buffer — cannot overflow (64*4096)
constexpr float C2 = 0.18033688011112042f;   // 0.125 * log2(e)

typedef __attribute__((ext_vector_type(8))) short bf16x8;
typedef __attribute__((ext_vector_type(4))) float f32x4;

__device__ inline unsigned short f2bf(float x) {
    union { float f; unsigned u; } v; v.f = x;
    unsigned r = v.u + 0x7fff + ((v.u >> 16) & 1);   // RNE
    return (unsigned short)(r >> 16);
}
__device__ inline float bf2f(unsigned short u) {
    union { unsigned u; float f; } v; v.u = ((unsigned)u) << 16;
    return v.f;
}
__device__ inline unsigned pk_bf16(float a, float b) {   // native cvt_pk
    float2 t; t.x = a; t.y = b;
    __hip_bfloat162 h = __float22bfloat162_rn(t);
    return *(unsigned*)&h;
}

// ---------------------------------------------------------------------------
// f32 -> bf16 elementwise. 8 elems/thread; grid = n/2048.
// ---------------------------------------------------------------------------
__global__ __launch_bounds__(256)
void cvt_bf16(const float* __restrict__ x, unsigned short* __restrict__ y)
{
    size_t i = ((size_t)blockIdx.x * 256 + threadIdx.x) * 8;
    float4 a = *(const float4*)(x + i);
    float4 b = *(const float4*)(x + i + 4);
    uint4 p;
    p.x = pk_bf16(a.x, a.y);
    p.y = pk_bf16(a.z, a.w);
    p.z = pk_bf16(b.x, b.y);
    p.w = pk_bf16(b.z, b.w);
    *(uint4*)(y + i) = p;
}

// ---------------------------------------------------------------------------
// Fused transpose+convert of the three 1024x1024 weights (z selects).
// ---------------------------------------------------------------------------
__global__ __launch_bounds__(256)
void transpose_cvt3(const float* __restrict__ W0, const float* __restrict__ W1,
                    const float* __restrict__ W2, unsigned short* __restrict__ T0,
                    unsigned short* __restrict__ T1, unsigned short* __restrict__ T2)
{
    const float* W = blockIdx.z == 0 ? W0 : (blockIdx.z == 1 ? W1 : W2);
    unsigned short* WT = blockIdx.z == 0 ? T0 : (blockIdx.z == 1 ? T1 : T2);
    __shared__ unsigned short T[64][72];
    const int tid = threadIdx.x;
    const int n0 = blockIdx.x * 64, k0 = blockIdx.y * 64;
    const int rr = tid >> 4, cc = tid & 15;
#pragma unroll
    for (int q2 = 0; q2 < 4; ++q2) {
        int kk = rr * 4 + q2;
        float4 v = *(const float4*)(W + (size_t)(k0 + kk) * Dm + n0 + cc * 4);
        T[cc * 4 + 0][kk] = f2bf(v.x);
        T[cc * 4 + 1][kk] = f2bf(v.y);
        T[cc * 4 + 2][kk] = f2bf(v.z);
        T[cc * 4 + 3][kk] = f2bf(v.w);
    }
    __syncthreads();
#pragma unroll
    for (int q2 = 0; q2 < 4; ++q2) {
        int nn = rr * 4 + q2;
        uint2 u;
        u.x = (unsigned)T[nn][cc * 4 + 0] | ((unsigned)T[nn][cc * 4 + 1] << 16);
        u.y = (unsigned)T[nn][cc * 4 + 2] | ((unsigned)T[nn][cc * 4 + 3] << 16);
        *(uint2*)(WT + (size_t)(n0 + nn) * Dm + k0 + cc * 4) = u;
    }
}

// ---------------------------------------------------------------------------
// bf16 MFMA GEMM, 128x128 tile, 512 thr = 8 waves (2m x 4n), BK=32.
// Dual-target via blockIdx.z. (Unchanged, proven.)
// ---------------------------------------------------------------------------
template<bool BF16OUT>
__global__ __launch_bounds__(512)
void gemm_bf16(const unsigned short* __restrict__ A,
               const unsigned short* BT0, const unsigned short* BT1,
               const float* bias0, const float* bias1,
               void* C0, void* C1, int N, int K)
{
    const unsigned short* BT = blockIdx.z ? BT1 : BT0;
    const float* bias = blockIdx.z ? bias1 : bias0;
    void* C = blockIdx.z ? C1 : C0;
    __shared__ __align__(16) unsigned short As[128 * 32];
    __shared__ __align__(16) unsigned short Bs[128 * 32];
    const int tid = threadIdx.x;
    const int l = tid & 63, w = tid >> 6;
    const int l15 = l & 15, l4 = l >> 4;
    const int wm = w >> 2, wn = w & 3;           // 2 x 4 wave grid
    const int row0 = blockIdx.y * 128, col0 = blockIdx.x * 128;

    f32x4 acc[4][2];
#pragma unroll
    for (int mi = 0; mi < 4; ++mi)
#pragma unroll
        for (int ni = 0; ni < 2; ++ni) acc[mi][ni] = (f32x4)(0.f);

    for (int k0 = 0; k0 < K; k0 += 32) {
        __syncthreads();
        {
            int r = tid >> 2, pc = tid & 3;
            uint4 vv = *(const uint4*)(A + (size_t)(row0 + r) * K + k0 + pc * 8);
            *(uint4*)&As[tid * 8] = vv;
        }
        {
            int r = tid >> 2, pc = tid & 3;
            uint4 vv = *(const uint4*)(BT + (size_t)(col0 + r) * K + k0 + pc * 8);
            *(uint4*)&Bs[tid * 8] = vv;
        }
        __syncthreads();

        bf16x8 af[4], bf[2];
#pragma unroll
        for (int mi = 0; mi < 4; ++mi)
            af[mi] = *(bf16x8*)&As[(wm * 64 + mi * 16 + l15) * 32 + l4 * 8];
#pragma unroll
        for (int ni = 0; ni < 2; ++ni)
            bf[ni] = *(bf16x8*)&Bs[(wn * 32 + ni * 16 + l15) * 32 + l4 * 8];
#pragma unroll
        for (int mi = 0; mi < 4; ++mi)
#pragma unroll
            for (int ni = 0; ni < 2; ++ni)
                acc[mi][ni] = __builtin_amdgcn_mfma_f32_16x16x32_bf16(af[mi], bf[ni], acc[mi][ni], 0, 0, 0);
    }

#pragma unroll
    for (int mi = 0; mi < 4; ++mi)
#pragma unroll
        for (int ni = 0; ni < 2; ++ni)
#pragma unroll
            for (int j = 0; j < 4; ++j) {
                int row = row0 + wm * 64 + mi * 16 + l4 * 4 + j;
                int col = col0 + wn * 32 + ni * 16 + l15;
                float vv = acc[mi][ni][j] + bias[col];
                if (BF16OUT)
                    ((unsigned short*)C)[(size_t)row * N + col] = f2bf(vv);
                else
                    ((float*)C)[(size_t)row * N + col] = vv;
            }
}

// ---------------------------------------------------------------------------
// Split-K f32 GEMM for vq: partial[z] = A[:, z*256:(z+1)*256] @ W-slice.
// ---------------------------------------------------------------------------
__global__ __launch_bounds__(256)
void gemm_vq_partial(const float* __restrict__ A, const float* __restrict__ W,
                     float* __restrict__ P)
{
    __shared__ float As[64][36];
    __shared__ float Ws[32][64];
    const int tid = threadIdx.x;
    const int row0 = blockIdx.y * 64, col0 = blockIdx.x * 64;
    const int kbase = blockIdx.z * 256;
    const int tr = tid >> 4, tc = tid & 15;
    float acc[4][4] = {};

    for (int k0 = kbase; k0 < kbase + 256; k0 += 32) {
        __syncthreads();
#pragma unroll
        for (int q2 = 0; q2 < 2; ++q2) {
            int oc = q2 * 256 + tid;
            int r = oc >> 3, c4 = (oc & 7) << 2;
            *(float4*)&As[r][c4] = *(const float4*)(A + (size_t)(row0 + r) * Dm + k0 + c4);
        }
#pragma unroll
        for (int q2 = 0; q2 < 2; ++q2) {
            int oc = q2 * 256 + tid;
            int r = oc >> 4, c4 = (oc & 15) << 2;
            *(float4*)&Ws[r][c4] = *(const float4*)(W + (size_t)(k0 + r) * DRr + col0 + c4);
        }
        __syncthreads();
#pragma unroll 8
        for (int kk = 0; kk < 32; ++kk) {
            float a[4];
#pragma unroll
            for (int i = 0; i < 4; ++i) a[i] = As[tr * 4 + i][kk];
            float4 bv = *(const float4*)&Ws[kk][tc * 4];
            float b[4] = {bv.x, bv.y, bv.z, bv.w};
#pragma unroll
            for (int i = 0; i < 4; ++i)
#pragma unroll
                for (int j = 0; j < 4; ++j)
                    acc[i][j] = fmaf(a[i], b[j], acc[i][j]);
        }
    }
    float* Pz = P + (size_t)blockIdx.z * Mrows * DRr;
#pragma unroll
    for (int i = 0; i < 4; ++i) {
        int r = row0 + tr * 4 + i;
        float4 ov = {acc[i][0], acc[i][1], acc[i][2], acc[i][3]};
        *(float4*)(Pz + (size_t)r * DRr + col0 + tc * 4) = ov;
    }
}

// ---------------------------------------------------------------------------
// Reduce split-K partials (fixed order) + bias -> vqb f32 and vq_hi bf16.
// ---------------------------------------------------------------------------
__global__ __launch_bounds__(256)
void reduce_vq(const float* __restrict__ P, const float* __restrict__ bias,
               float* __restrict__ vqb, unsigned short* __restrict__ vq_hi)
{
    const size_t i4 = ((size_t)blockIdx.x * 256 + threadIdx.x) * 4;
    const int col = (int)(i4 & 127);
    const size_t stride = (size_t)Mrows * DRr;
    float4 s = *(const float4*)(P + i4);
#pragma unroll
    for (int z = 1; z < 4; ++z) {
        float4 p = *(const float4*)(P + stride * z + i4);
        s.x += p.x; s.y += p.y; s.z += p.z; s.w += p.w;
    }
    float4 bv = *(const float4*)(bias + col);
    s.x += bv.x; s.y += bv.y; s.z += bv.z; s.w += bv.w;
    *(float4*)(vqb + i4) = s;
    uint2 u;
    u.x = pk_bf16(s.x, s.y);
    u.y = pk_bf16(s.z, s.w);
    *(uint2*)(vq_hi + i4) = u;
}

// ---------------------------------------------------------------------------
// Screen: A-resident col-sweep, NO atomics (R11 compute core, pushes removed).
// Grid (NV/512=16, Mrows/128=32); 512 thr = 8 waves, wave w owns rows
// [row0 + w*16, +16) with its A-frags (whole K=128) in registers.
// B 64-key tiles double-buffered in LDS (32KB) with T14 reg-prefetch;
// 16 MFMAs/wave/tile, 8 tiles/block. Per 2 tiles (=128 keys) the per-row
// maxima (wave-local: in-reg + 4 shuffles) are stored to rtm[tile][row].
// ---------------------------------------------------------------------------
__global__ __launch_bounds__(512)
void sim_max(const unsigned short* __restrict__ vq_hi,
             const unsigned short* __restrict__ vk_hi,
             float* __restrict__ rtm)
{
    __shared__ __align__(16) unsigned short Buf[2][64 * 128];   // 32KB dbuf
    const int tid = threadIdx.x;
    const int l = tid & 63, w = tid >> 6;
    const int l15 = l & 15, l4 = l >> 4;
    const int row0 = blockIdx.y * 128;
    const int key0 = blockIdx.x * 512;

    // A fragments (16 rows x K=128) straight from global, once
    bf16x8 af[4];
    {
        const unsigned short* ap = vq_hi + (size_t)(row0 + w * 16 + l15) * 128 + l4 * 8;
#pragma unroll
        for (int kk = 0; kk < 4; ++kk) af[kk] = *(const bf16x8*)(ap + kk * 32);
    }

    // stage B tile 0 (source chunk-XOR swizzled, LDS linear)
#pragma unroll
    for (int q2 = 0; q2 < 2; ++q2) {
        int oc = q2 * 512 + tid;
        int r = oc >> 4, pc = oc & 15;
        int lc = pc ^ (r & 15);
        uint4 vv = *(const uint4*)(vk_hi + (size_t)(key0 + r) * 128 + lc * 8);
        *(uint4*)&Buf[0][oc * 8] = vv;
    }
    __syncthreads();

    float tmax[4];

    for (int t = 0; t < 8; ++t) {
        const int cur = t & 1;
        uint4 st[2];
        if (t + 1 < 8) {       // T14: issue next tile's loads before compute
#pragma unroll
            for (int q2 = 0; q2 < 2; ++q2) {
                int oc = q2 * 512 + tid;
                int r = oc >> 4, pc = oc & 15;
                int lc = pc ^ (r & 15);
                st[q2] = *(const uint4*)(vk_hi + (size_t)(key0 + (t + 1) * 64 + r) * 128 + lc * 8);
            }
        }
        // 16 MFMAs/wave: all 64 keys of the tile for this wave's 16 rows
        f32x4 acc[4];
#pragma unroll
        for (int ni = 0; ni < 4; ++ni) {
            const int key16 = ni * 16 + l15;
            bf16x8 bfr[4];
#pragma unroll
            for (int kk = 0; kk < 4; ++kk)
                bfr[kk] = *(bf16x8*)&Buf[cur][key16 * 128 + (((kk * 4 + l4) ^ (key16 & 15)) * 8)];
            f32x4 a = (f32x4)(0.f);
#pragma unroll
            for (int kk = 0; kk < 4; ++kk)
                a = __builtin_amdgcn_mfma_f32_16x16x32_bf16(af[kk], bfr[kk], a, 0, 0, 0);
            acc[ni] = a;
        }
        // per-row maxima: rows = w*16 + l4*4 + j, reduce over keys (ni, l15)
        float tm[4];
#pragma unroll
        for (int j = 0; j < 4; ++j)
            tm[j] = fmaxf(fmaxf(acc[0][j], acc[1][j]), fmaxf(acc[2][j], acc[3][j]));
#pragma unroll
        for (int off = 1; off < 16; off <<= 1)
#pragma unroll
            for (int j = 0; j < 4; ++j)
                tm[j] = fmaxf(tm[j], __shfl_xor(tm[j], off));
        if ((t & 1) == 0) {
#pragma unroll
            for (int j = 0; j < 4; ++j) tmax[j] = tm[j];
        } else {
            if (l15 == 0) {
                const size_t tbase = (size_t)(blockIdx.x * 4 + (t >> 1)) * Mrows;
#pragma unroll
                for (int j = 0; j < 4; ++j)
                    rtm[tbase + row0 + w * 16 + l4 * 4 + j] = fmaxf(tmax[j], tm[j]);
            }
        }
        if (t + 1 < 8) {       // write prefetched tile into the other buffer
#pragma unroll
            for (int q2 = 0; q2 < 2; ++q2) {
                int oc = q2 * 512 + tid;
                *(uint4*)&Buf[cur ^ 1][oc * 8] = st[q2];
            }
        }
        __syncthreads();
    }
}

// ---------------------------------------------------------------------------
// thr[row] = max over 64 tile-maxima - MARGIN (rtm transposed: [tile][row]).
// ---------------------------------------------------------------------------
__global__ __launch_bounds__(256)
void sim_combine2(const float* __restrict__ rtm, float* __restrict__ thr)
{
    int r = blockIdx.x * 256 + threadIdx.x;
    if (r >= Mrows) return;
    float m = -INFINITY;
#pragma unroll 8
    for (int c = 0; c < 64; ++c)
        m = fmaxf(m, rtm[(size_t)c * Mrows + r]);
    thr[r] = m - MARGIN;
}

// ---------------------------------------------------------------------------
// Collect qualifying (row,tile) pairs. One thread per rtm entry (262144);
// ballot-aggregated pushes (~4300 selected -> ~1 atomic per nonempty wave).
// ---------------------------------------------------------------------------
__global__ __launch_bounds__(256)
void collect_pairs(const float* __restrict__ rtm, const float* __restrict__ thr,
                   unsigned* __restrict__ cnt, unsigned* __restrict__ pairs)
{
    const int idx = blockIdx.x * 256 + threadIdx.x;
    const int tile = idx >> 12, row = idx & 4095;
    const bool pred = rtm[(size_t)tile * Mrows + row] >= thr[row];
    unsigned long long mask = __ballot(pred);
    if (mask) {
        const int lane = threadIdx.x & 63;
        const int leader = __ffsll((long long)mask) - 1;
        unsigned base = 0;
        if (lane == leader) base = atomicAdd(cnt, (unsigned)__popcll(mask));
        base = (unsigned)__shfl((int)base, leader);
        if (pred) {
            unsigned off = (unsigned)__popcll(mask & ((1ull << lane) - 1ull));
            pairs[base + off] = ((unsigned)row << 6) | (unsigned)tile;
        }
    }
}

// ---------------------------------------------------------------------------
// Exact f32 rescore, one block per (row,tile) pair (grid-stride).
// ---------------------------------------------------------------------------
__global__ __launch_bounds__(256)
void rescore_pair(const unsigned* __restrict__ pairs, const unsigned* __restrict__ cnt,
                  const float* __restrict__ vq, const float* __restrict__ vkeys,
                  unsigned long long* __restrict__ best)
{
    __shared__ float vqs[128];
    __shared__ float part[256];
    const int tid = threadIdx.x;
    const unsigned n = min(*cnt, (unsigned)CAP);
    for (unsigned i = blockIdx.x; i < n; i += gridDim.x) {
        const unsigned p = pairs[i];
        const unsigned row = p >> 6, tile = p & 63u;
        if (tid < 32) {
            float4 v = *(const float4*)(vq + (size_t)row * 128 + tid * 4);
            *(float4*)&vqs[tid * 4] = v;
        }
        __syncthreads();
        const int k = tid & 127, h = (tid >> 7) * 64;
        const float* kp = vkeys + (size_t)(tile * 128 + k) * 128 + h;
        float s = 0.f;
#pragma unroll
        for (int d = 0; d < 64; d += 4) {
            float4 kv = *(const float4*)(kp + d);
            s = fmaf(vqs[h + d + 0], kv.x, s);
            s = fmaf(vqs[h + d + 1], kv.y, s);
            s = fmaf(vqs[h + d + 2], kv.z, s);
            s = fmaf(vqs[h + d + 3], kv.w, s);
        }
        part[tid] = s;
        __syncthreads();
        if (tid < 64) {
            float s0 = part[tid] + part[tid + 128];
            float s1 = part[tid + 64] + part[tid + 192];
            float bs = s0; int bk = tid;
            if (s1 > s0) { bs = s1; bk = tid + 64; }
#pragma unroll
            for (int off = 1; off < 64; off <<= 1) {
                float os = __shfl_xor(bs, off);
                int ok = __shfl_xor(bk, off);
                if (os > bs || (os == bs && ok < bk)) { bs = os; bk = ok; }
            }
            if (tid == 0) {
                unsigned key = tile * 128 + bk;
                unsigned fb = __float_as_uint(bs);
                fb = (fb & 0x80000000u) ? ~fb : (fb | 0x80000000u);
                unsigned long long enc = ((unsigned long long)fb << 32) | (unsigned)(~key);
                atomicMax(best + row, enc);
            }
        }
        __syncthreads();
    }
}

// ---------------------------------------------------------------------------
// Fused build + transpose: VT[(b*16+h)*64 + d][key] = bf16(hs * vembed[idx]).
// ---------------------------------------------------------------------------
__global__ __launch_bounds__(256)
void build_vt(const float* __restrict__ hs, const float* __restrict__ vembed,
              const unsigned long long* __restrict__ best,
              unsigned short* __restrict__ vt)
{
    __shared__ unsigned short T[64][73];
    __shared__ int ids[64];
    const int tid = threadIdx.x;
    const int kt = blockIdx.x;
    const int bh = blockIdx.y;
    const int b = bh >> 4, h = bh & 15;
    if (tid < 64) {
        int row = b * Ss + kt * 64 + tid;
        ids[tid] = (int)((~(unsigned)(best[row] & 0xFFFFFFFFull)) & 8191u);
    }
    __syncthreads();
    {
        int r = tid >> 2, c16 = (tid & 3) * 16;
        size_t hrow = (size_t)(b * Ss + kt * 64 + r) * Dm + h * HDd + c16;
        size_t erow = (size_t)ids[r] * Dm + h * HDd + c16;
#pragma unroll
        for (int q2 = 0; q2 < 4; ++q2) {
            float4 a = *(const float4*)(hs + hrow + q2 * 4);
            float4 e = *(const float4*)(vembed + erow + q2 * 4);
            T[r][c16 + q2 * 4 + 0] = f2bf(a.x * e.x);
            T[r][c16 + q2 * 4 + 1] = f2bf(a.y * e.y);
            T[r][c16 + q2 * 4 + 2] = f2bf(a.z * e.z);
            T[r][c16 + q2 * 4 + 3] = f2bf(a.w * e.w);
        }
    }
    __syncthreads();
    {
        int d = tid >> 2, kc = (tid & 3) * 16;
        unsigned short ob[16];
#pragma unroll
        for (int i = 0; i < 16; ++i) ob[i] = T[kc + i][d];
        unsigned short* op = vt + ((size_t)(b * Hh + h) * HDd + d) * Ss + kt * 64 + kc;
        *(uint4*)op = *(uint4*)&ob[0];
        *(uint4*)(op + 8) = *(uint4*)&ob[8];
    }
}

// ---------------------------------------------------------------------------
// meanv[b][h*64+d] from VT row sums (fully-masked-row substitution value).
// ---------------------------------------------------------------------------
__global__ __launch_bounds__(256)
void mean_vt(const unsigned short* __restrict__ vt, float* __restrict__ mv)
{
    const int bh = blockIdx.x;
    const int b = bh >> 4, h = bh & 15;
    const int d = threadIdx.x >> 2, part = threadIdx.x & 3;
    const unsigned short* row = vt + ((size_t)bh * HDd + d) * Ss + part * 512;
    float s = 0.f;
    for (int j = 0; j < 512; j += 8) {
        uint4 u = *(const uint4*)(row + j);
        const unsigned uu[4] = {u.x, u.y, u.z, u.w};
#pragma unroll
        for (int m = 0; m < 4; ++m) {
            s += bf2f((unsigned short)(uu[m] & 0xffff));
            s += bf2f((unsigned short)(uu[m] >> 16));
        }
    }
    s += __shfl_xor(s, 1);
    s += __shfl_xor(s, 2);
    if (part == 0) mv[b * Dm + h * HDd + d] = s * (1.f / 2048.f);
}

// ---------------------------------------------------------------------------
// bf16 MFMA flash attention v5: double-buffered K/VT + T14 reg-prefetch,
// ONE barrier per tile-step. Buffer selection via byte offsets (no LDS
// pointer arrays — hipcc rejects addrspacecast in static initializers).
// ---------------------------------------------------------------------------
__global__ __launch_bounds__(512)
void attn_mfma5(const unsigned short* __restrict__ q, const unsigned short* __restrict__ k,
                const unsigned short* __restrict__ vt, const float* __restrict__ am,
                const float* __restrict__ dmask, const float* __restrict__ meanv,
                unsigned short* __restrict__ o)
{
    __shared__ __align__(16) unsigned char smem[57344]; // K dbuf 16K | VT dbuf 16K | P 16K | amdm 8K
    __shared__ float uniflag[128];
    unsigned char* Psm = smem + 32768;
    float* amdmf = (float*)(smem + 49152);

    const int tid = threadIdx.x;
    const int l = tid & 63, w = tid >> 6;
    const int l15 = l & 15, l4 = l >> 4;
    const int lin = blockIdx.x + (blockIdx.y << 4) + (blockIdx.z << 8);
    const int half = lin >> 8, rem = lin & 255;
    const int qtb = rem & 15;
    const int qt = half ? (15 - qtb) : qtb;
    const int h = rem >> 4;
    const int b = half;
    const int row0 = qt * 128;

    {   // mask table: 0 or MIN_D per key
        int j = tid * 4;
        float4 a = *(const float4*)(am + b * Ss + j);
        float4 d = *(const float4*)(dmask + h * Ss + j);
        float4 m;
        m.x = (a.x * d.x == 0.f) ? MIN_D : 0.f;
        m.y = (a.y * d.y == 0.f) ? MIN_D : 0.f;
        m.z = (a.z * d.z == 0.f) ? MIN_D : 0.f;
        m.w = (a.w * d.w == 0.f) ? MIN_D : 0.f;
        *(float4*)&amdmf[j] = m;
    }

    const int qloc = w * 16 + l15;
    const int qrow = row0 + qloc;
    bf16x8 qf[2];
    {
        const unsigned short* qp = q + ((size_t)(b * Ss + qrow)) * Dm + h * HDd + l4 * 8;
        qf[0] = *(const bf16x8*)qp;
        qf[1] = *(const bf16x8*)(qp + 32);
    }

    // staging addresses (per thread: one 16B chunk of K, one of VT)
    const int skey = tid >> 3, spc = tid & 7;
    const int slk = spc ^ (skey & 7);       // K source chunk (swizzled)
    const int svd = tid >> 3;               // VT row (d)
    const int slv = spc ^ (svd & 7);        // VT source chunk

    // prologue: stage tile 0 into buffers 0
    {
        uint4 kv = *(const uint4*)(k + ((size_t)(b * Ss + skey)) * Dm + h * HDd + slk * 8);
        *(uint4*)&smem[tid * 16] = kv;
        uint4 vv = *(const uint4*)(vt + ((size_t)(b * Hh + h) * HDd + svd) * Ss + slv * 8);
        *(uint4*)&smem[16384 + tid * 16] = vv;
    }
    __syncthreads();

    f32x4 acc[4];
#pragma unroll
    for (int d2 = 0; d2 < 4; ++d2) acc[d2] = (f32x4)(0.f);
    float mrun = -INFINITY, lrun = 0.f;
    const int ktmax = 2 * qt + 1;

    for (int kt = 0; kt <= ktmax; ++kt) {
        const unsigned cb = (unsigned)(kt & 1) << 13;   // 0 or 8192
        unsigned char* Ksm = smem + cb;
        unsigned char* Vsm = smem + 16384 + cb;
        // T14: issue next tile's loads into registers before compute
        uint4 kst, vst;
        if (kt < ktmax) {
            kst = *(const uint4*)(k + ((size_t)(b * Ss + (kt + 1) * 64 + skey)) * Dm
                                  + h * HDd + slk * 8);
            vst = *(const uint4*)(vt + ((size_t)(b * Hh + h) * HDd + svd) * Ss
                                  + (kt + 1) * 64 + slv * 8);
        }

        // S^T = K Q^T
        f32x4 sreg[4];
#pragma unroll
        for (int kb = 0; kb < 4; ++kb) {
            const int key16 = kb * 16 + l15;
            const int sw = key16 & 7;
            bf16x8 k0 = *(bf16x8*)&Ksm[key16 * 128 + ((l4 ^ sw) * 16)];
            bf16x8 k1 = *(bf16x8*)&Ksm[key16 * 128 + (((4 + l4) ^ sw) * 16)];
            f32x4 s = (f32x4)(0.f);
            s = __builtin_amdgcn_mfma_f32_16x16x32_bf16(k0, qf[0], s, 0, 0, 0);
            s = __builtin_amdgcn_mfma_f32_16x16x32_bf16(k1, qf[1], s, 0, 0, 0);
            sreg[kb] = s;
        }

        float sv[16];
#pragma unroll
        for (int kb = 0; kb < 4; ++kb)
#pragma unroll
            for (int r = 0; r < 4; ++r) {
                const int key = kt * 64 + kb * 16 + l4 * 4 + r;
                const float mval = (key > qrow) ? MIN_D : amdmf[key];
                sv[kb * 4 + r] = fmaf(sreg[kb][r], C2, mval);
            }

        float pm = fmaxf(fmaxf(sv[0], sv[1]), sv[2]);
        pm = fmaxf(fmaxf(pm, sv[3]), fmaxf(sv[4], sv[5]));
        pm = fmaxf(fmaxf(pm, sv[6]), fmaxf(sv[7], sv[8]));
        pm = fmaxf(fmaxf(pm, sv[9]), fmaxf(sv[10], sv[11]));
        pm = fmaxf(fmaxf(pm, sv[12]), fmaxf(sv[13], sv[14]));
        pm = fmaxf(pm, sv[15]);
        pm = fmaxf(pm, __shfl_xor(pm, 16));
        pm = fmaxf(pm, __shfl_xor(pm, 32));

        if (__any(pm > mrun + 8.f)) {       // defer-rescale (T13)
            const float mn = fmaxf(mrun, pm);
            const float sc = __builtin_amdgcn_exp2f(mrun - mn);
            lrun *= sc;
#pragma unroll
            for (int d2 = 0; d2 < 4; ++d2) acc[d2] *= sc;
            mrun = mn;
        }

        float p[16], rs = 0.f;
#pragma unroll
        for (int i = 0; i < 16; ++i) {
            p[i] = __builtin_amdgcn_exp2f(sv[i] - mrun);
            rs += p[i];
        }
        rs += __shfl_xor(rs, 16);
        rs += __shfl_xor(rs, 32);
        lrun += rs;

        // P store (wave-private rows; same-wave write->read, no barrier)
        const unsigned pswz = (l15 & 7) << 4;
#pragma unroll
        for (int kb = 0; kb < 4; ++kb) {
            uint2 u;
            u.x = pk_bf16(p[kb * 4 + 0], p[kb * 4 + 1]);
            u.y = pk_bf16(p[kb * 4 + 2], p[kb * 4 + 3]);
            *(uint2*)&Psm[qloc * 128 + ((kb * 32 + l4 * 8) ^ pswz)] = u;
        }

        // O^T += V^T P^T
#pragma unroll
        for (int ks = 0; ks < 2; ++ks) {
            bf16x8 pa = *(bf16x8*)&Psm[qloc * 128 + ((ks * 64 + l4 * 16) ^ pswz)];
#pragma unroll
            for (int d2 = 0; d2 < 4; ++d2) {
                const int dd = d2 * 16 + l15;
                bf16x8 vb = *(bf16x8*)&Vsm[dd * 128 + ((ks * 64 + l4 * 16) ^ ((dd & 7) << 4))];
                acc[d2] = __builtin_amdgcn_mfma_f32_16x16x32_bf16(vb, pa, acc[d2], 0, 0, 0);
            }
        }

        // write prefetched tile into the other buffers; one barrier per iter
        if (kt < ktmax) {
            const unsigned nb = cb ^ 8192u;
            *(uint4*)&smem[nb + tid * 16] = kst;
            *(uint4*)&smem[16384 + nb + tid * 16] = vst;
        }
        __syncthreads();
    }

    // epilogue: bf16 transpose through LDS, coalesced stores
    const float inv = 1.f / lrun;
    const bool uni = (mrun <= -1e37f);
    unsigned short* stg = (unsigned short*)smem;
    uniflag[qloc] = uni ? 1.f : 0.f;
#pragma unroll
    for (int d2 = 0; d2 < 4; ++d2) {
        uint2 u;
        u.x = pk_bf16(acc[d2][0] * inv, acc[d2][1] * inv);
        u.y = pk_bf16(acc[d2][2] * inv, acc[d2][3] * inv);
        *(uint2*)&stg[qloc * 72 + d2 * 16 + l4 * 4] = u;
    }
    __syncthreads();
    {
        const int r = tid >> 2, c16 = (tid & 3) * 16;
        const bool u = uniflag[r] != 0.f;
        uint4 o0, o1;
        if (u) {
            unsigned short ob[16];
#pragma unroll
            for (int i = 0; i < 16; ++i)
                ob[i] = f2bf(meanv[b * Dm + h * HDd + c16 + i]);
            o0 = *(uint4*)&ob[0];
            o1 = *(uint4*)&ob[8];
        } else {
            o0 = *(uint4*)&stg[r * 72 + c16];
            o1 = *(uint4*)&stg[r * 72 + c16 + 8];
        }
        unsigned short* op = o + ((size_t)(b * Ss + row0 + r)) * Dm + h * HDd + c16;
        *(uint4*)op = o0;
        *(uint4*)(op + 8) = o1;
    }
}

// ---------------------------------------------------------------------------
extern "C" void kernel_launch(void* const* d_in, const int* in_sizes, int n_in,
                              void* d_out, int out_size, void* d_ws, size_t ws_size,
                              hipStream_t stream)
{
    const float* hs     = (const float*)d_in[0];
    const float* amask  = (const float*)d_in[1];
    const float* Wq     = (const float*)d_in[2];
    const float* bq     = (const float*)d_in[3];
    const float* Wk     = (const float*)d_in[4];
    const float* bk     = (const float*)d_in[5];
    const float* dmask  = (const float*)d_in[6];
    const float* Wvq    = (const float*)d_in[7];
    const float* bvq    = (const float*)d_in[8];
    const float* vkeys  = (const float*)d_in[9];
    const float* vembed = (const float*)d_in[10];
    const float* Wo     = (const float*)d_in[11];
    const float* bo     = (const float*)d_in[12];
    float* out = (float*)d_out;

    char* w = (char*)d_ws;
    size_t off = 0;
    auto take = [&](size_t n) { char* p = w + off; off = (off + n + 255) & ~(size_t)255; return p; };
    unsigned short* hsbf  = (unsigned short*)take((size_t)Mrows * Dm * 2);
    unsigned short* WqT   = (unsigned short*)take((size_t)Dm * Dm * 2);
    unsigned short* WkT   = (unsigned short*)take((size_t)Dm * Dm * 2);
    unsigned short* WoT   = (unsigned short*)take((size_t)Dm * Dm * 2);
    unsigned short* qbf   = (unsigned short*)take((size_t)Mrows * Dm * 2);
    unsigned short* kbf   = (unsigned short*)take((size_t)Mrows * Dm * 2);
    unsigned short* vtb   = (unsigned short*)take((size_t)Mrows * Dm * 2);   // VT
    unsigned short* attno = (unsigned short*)take((size_t)Mrows * Dm * 2);
    float* vqp   = (float*)take((size_t)4 * Mrows * DRr * 4);               // split-K partials
    float* vqb   = (float*)take((size_t)Mrows * DRr * 4);
    unsigned short* vq_hi = (unsigned short*)take((size_t)Mrows * DRr * 2);
    unsigned short* vk_hi = (unsigned short*)take((size_t)NV * DRr * 2);
    float* rtm   = (float*)take((size_t)64 * Mrows * 4);                    // [tile][row]
    float* thr   = (float*)take((size_t)Mrows * 4);
    unsigned* cnt = (unsigned*)take(256);
    unsigned* pairs = (unsigned*)take((size_t)CAP * 4);
    unsigned long long* best = (unsigned long long*)take((size_t)Mrows * 8);
    float* mvb   = (float*)take((size_t)Bb * Dm * 4);

    (void)hipMemsetAsync(cnt, 0, 4, stream);
    (void)hipMemsetAsync(best, 0, (size_t)Mrows * 8, stream);

    dim3 blk(256);
    // dtype prep
    cvt_bf16<<<dim3(Mrows * Dm / 2048), blk, 0, stream>>>(hs, hsbf);
    transpose_cvt3<<<dim3(Dm / 64, Dm / 64, 3), blk, 0, stream>>>(Wq, Wk, Wo, WqT, WkT, WoT);
    // Q,K projections fused via z
    gemm_bf16<true><<<dim3(Dm / 128, Mrows / 128, 2), dim3(512), 0, stream>>>(
        hsbf, WqT, WkT, bq, bk, qbf, kbf, Dm, Dm);
    // retrieval: split-K exact vq, reduce(+bf16 copy), A-resident max screen,
    // pair collection, exact per-pair rescore
    gemm_vq_partial<<<dim3(DRr / 64, Mrows / 64, 4), blk, 0, stream>>>(hs, Wvq, vqp);
    reduce_vq<<<dim3(Mrows * DRr / 1024), blk, 0, stream>>>(vqp, bvq, vqb, vq_hi);
    cvt_bf16<<<dim3(NV * DRr / 2048), blk, 0, stream>>>(vkeys, vk_hi);
    sim_max<<<dim3(NV / 512, Mrows / 128), dim3(512), 0, stream>>>(vq_hi, vk_hi, rtm);
    sim_combine2<<<dim3(Mrows / 256), blk, 0, stream>>>(rtm, thr);
    collect_pairs<<<dim3(64 * Mrows / 256), blk, 0, stream>>>(rtm, thr, cnt, pairs);
    rescore_pair<<<dim3(2048), blk, 0, stream>>>(pairs, cnt, vqb, vkeys, best);
    // fused build+transpose of V, then mean
    build_vt<<<dim3(Ss / 64, Bb * Hh), blk, 0, stream>>>(hs, vembed, best, vtb);
    mean_vt<<<dim3(Bb * Hh), blk, 0, stream>>>(vtb, mvb);
    // attention (512 threads, double-buffered)
    attn_mfma5<<<dim3(Ss / 128, Hh, Bb), dim3(512), 0, stream>>>(
        qbf, kbf, vtb, amask, dmask, mvb, attno);
    // output projection (f32 out)
    gemm_bf16<false><<<dim3(Dm / 128, Mrows / 128, 1), dim3(512), 0, stream>>>(
        attno, WoT, WoT, bo, bo, out, out, Dm, Dm);
}

// Round 16
// 268.060 us; speedup vs baseline: 12.2379x; 1.0315x over previous
//
#include <hip/hip_runtime.h>
#include <hip/hip_bf16.h>
#include <math.h>

#define MIN_D (-3.402823466e+38f)

constexpr int Bb = 2, Ss = 2048, Dm = 1024, Hh = 16, HDd = 64, NV = 8192, DRr = 128;
constexpr int Mrows = Bb * Ss;   // 4096
constexpr float MARGIN = 0.01f;  // >> 2x bf16-MFMA sim error (~1e-3 RSS)
constexpr int CAP = 262144;      // (row,tile) pair buffer — cannot overflow (64*4096)
constexpr float C2 = 0.18033688011112042f;   // 0.125 * log2(e)

typedef __attribute__((ext_vector_type(8))) short bf16x8;
typedef __attribute__((ext_vector_type(4))) float f32x4;

__device__ inline unsigned short f2bf(float x) {
    union { float f; unsigned u; } v; v.f = x;
    unsigned r = v.u + 0x7fff + ((v.u >> 16) & 1);   // RNE
    return (unsigned short)(r >> 16);
}
__device__ inline float bf2f(unsigned short u) {
    union { unsigned u; float f; } v; v.u = ((unsigned)u) << 16;
    return v.f;
}
__device__ inline unsigned pk_bf16(float a, float b) {   // native cvt_pk
    float2 t; t.x = a; t.y = b;
    __hip_bfloat162 h = __float22bfloat162_rn(t);
    return *(unsigned*)&h;
}

// ---------------------------------------------------------------------------
// f32 -> bf16 elementwise. 8 elems/thread; grid = n/2048.
// ---------------------------------------------------------------------------
__global__ __launch_bounds__(256)
void cvt_bf16(const float* __restrict__ x, unsigned short* __restrict__ y)
{
    size_t i = ((size_t)blockIdx.x * 256 + threadIdx.x) * 8;
    float4 a = *(const float4*)(x + i);
    float4 b = *(const float4*)(x + i + 4);
    uint4 p;
    p.x = pk_bf16(a.x, a.y);
    p.y = pk_bf16(a.z, a.w);
    p.z = pk_bf16(b.x, b.y);
    p.w = pk_bf16(b.z, b.w);
    *(uint4*)(y + i) = p;
}

// ---------------------------------------------------------------------------
// Fused transpose+convert of the three 1024x1024 weights (z selects).
// ---------------------------------------------------------------------------
__global__ __launch_bounds__(256)
void transpose_cvt3(const float* __restrict__ W0, const float* __restrict__ W1,
                    const float* __restrict__ W2, unsigned short* __restrict__ T0,
                    unsigned short* __restrict__ T1, unsigned short* __restrict__ T2)
{
    const float* W = blockIdx.z == 0 ? W0 : (blockIdx.z == 1 ? W1 : W2);
    unsigned short* WT = blockIdx.z == 0 ? T0 : (blockIdx.z == 1 ? T1 : T2);
    __shared__ unsigned short T[64][72];
    const int tid = threadIdx.x;
    const int n0 = blockIdx.x * 64, k0 = blockIdx.y * 64;
    const int rr = tid >> 4, cc = tid & 15;
#pragma unroll
    for (int q2 = 0; q2 < 4; ++q2) {
        int kk = rr * 4 + q2;
        float4 v = *(const float4*)(W + (size_t)(k0 + kk) * Dm + n0 + cc * 4);
        T[cc * 4 + 0][kk] = f2bf(v.x);
        T[cc * 4 + 1][kk] = f2bf(v.y);
        T[cc * 4 + 2][kk] = f2bf(v.z);
        T[cc * 4 + 3][kk] = f2bf(v.w);
    }
    __syncthreads();
#pragma unroll
    for (int q2 = 0; q2 < 4; ++q2) {
        int nn = rr * 4 + q2;
        uint2 u;
        u.x = (unsigned)T[nn][cc * 4 + 0] | ((unsigned)T[nn][cc * 4 + 1] << 16);
        u.y = (unsigned)T[nn][cc * 4 + 2] | ((unsigned)T[nn][cc * 4 + 3] << 16);
        *(uint2*)(WT + (size_t)(n0 + nn) * Dm + k0 + cc * 4) = u;
    }
}

// ---------------------------------------------------------------------------
// bf16 MFMA GEMM v2: 128x128 tile, 512 thr = 8 waves (2m x 4n), BK=32,
// double-buffered LDS + T14 reg-prefetch, ONE barrier per K-iter
// (attn5-proven pattern; buffer select via byte offsets).
// Dual-target via blockIdx.z.
// ---------------------------------------------------------------------------
template<bool BF16OUT>
__global__ __launch_bounds__(512)
void gemm_bf16(const unsigned short* __restrict__ A,
               const unsigned short* BT0, const unsigned short* BT1,
               const float* bias0, const float* bias1,
               void* C0, void* C1, int N, int K)
{
    const unsigned short* BT = blockIdx.z ? BT1 : BT0;
    const float* bias = blockIdx.z ? bias1 : bias0;
    void* C = blockIdx.z ? C1 : C0;
    __shared__ __align__(16) unsigned char gsm[32768];  // A dbuf 16K | B dbuf 16K
    const int tid = threadIdx.x;
    const int l = tid & 63, w = tid >> 6;
    const int l15 = l & 15, l4 = l >> 4;
    const int wm = w >> 2, wn = w & 3;           // 2 x 4 wave grid
    const int row0 = blockIdx.y * 128, col0 = blockIdx.x * 128;

    // per-thread staging addresses (one 16B chunk of A, one of B per iter)
    const int sr = tid >> 2, spc = tid & 3;
    const unsigned short* Ap = A + (size_t)(row0 + sr) * K + spc * 8;
    const unsigned short* Bp = BT + (size_t)(col0 + sr) * K + spc * 8;

    f32x4 acc[4][2];
#pragma unroll
    for (int mi = 0; mi < 4; ++mi)
#pragma unroll
        for (int ni = 0; ni < 2; ++ni) acc[mi][ni] = (f32x4)(0.f);

    // prologue: stage k-tile 0 into buffers 0
    {
        uint4 av = *(const uint4*)Ap;
        uint4 bv = *(const uint4*)Bp;
        *(uint4*)&gsm[tid * 16] = av;
        *(uint4*)&gsm[16384 + tid * 16] = bv;
    }
    __syncthreads();

    const int iters = K >> 5;
    for (int it = 0; it < iters; ++it) {
        const unsigned cb = (unsigned)(it & 1) << 13;   // 0 or 8192
        unsigned short* As = (unsigned short*)(gsm + cb);
        unsigned short* Bs = (unsigned short*)(gsm + 16384 + cb);
        // T14: issue next k-tile's loads before compute
        uint4 ast, bst;
        if (it + 1 < iters) {
            ast = *(const uint4*)(Ap + (it + 1) * 32);
            bst = *(const uint4*)(Bp + (it + 1) * 32);
        }

        bf16x8 af[4], bf[2];
#pragma unroll
        for (int mi = 0; mi < 4; ++mi)
            af[mi] = *(bf16x8*)&As[(wm * 64 + mi * 16 + l15) * 32 + l4 * 8];
#pragma unroll
        for (int ni = 0; ni < 2; ++ni)
            bf[ni] = *(bf16x8*)&Bs[(wn * 32 + ni * 16 + l15) * 32 + l4 * 8];
#pragma unroll
        for (int mi = 0; mi < 4; ++mi)
#pragma unroll
            for (int ni = 0; ni < 2; ++ni)
                acc[mi][ni] = __builtin_amdgcn_mfma_f32_16x16x32_bf16(af[mi], bf[ni], acc[mi][ni], 0, 0, 0);

        // write prefetched k-tile into the other buffers; one barrier per iter
        if (it + 1 < iters) {
            const unsigned nb = cb ^ 8192u;
            *(uint4*)&gsm[nb + tid * 16] = ast;
            *(uint4*)&gsm[16384 + nb + tid * 16] = bst;
        }
        __syncthreads();
    }

#pragma unroll
    for (int mi = 0; mi < 4; ++mi)
#pragma unroll
        for (int ni = 0; ni < 2; ++ni)
#pragma unroll
            for (int j = 0; j < 4; ++j) {
                int row = row0 + wm * 64 + mi * 16 + l4 * 4 + j;
                int col = col0 + wn * 32 + ni * 16 + l15;
                float vv = acc[mi][ni][j] + bias[col];
                if (BF16OUT)
                    ((unsigned short*)C)[(size_t)row * N + col] = f2bf(vv);
                else
                    ((float*)C)[(size_t)row * N + col] = vv;
            }
}

// ---------------------------------------------------------------------------
// Split-K f32 GEMM for vq: partial[z] = A[:, z*256:(z+1)*256] @ W-slice.
// ---------------------------------------------------------------------------
__global__ __launch_bounds__(256)
void gemm_vq_partial(const float* __restrict__ A, const float* __restrict__ W,
                     float* __restrict__ P)
{
    __shared__ float As[64][36];
    __shared__ float Ws[32][64];
    const int tid = threadIdx.x;
    const int row0 = blockIdx.y * 64, col0 = blockIdx.x * 64;
    const int kbase = blockIdx.z * 256;
    const int tr = tid >> 4, tc = tid & 15;
    float acc[4][4] = {};

    for (int k0 = kbase; k0 < kbase + 256; k0 += 32) {
        __syncthreads();
#pragma unroll
        for (int q2 = 0; q2 < 2; ++q2) {
            int oc = q2 * 256 + tid;
            int r = oc >> 3, c4 = (oc & 7) << 2;
            *(float4*)&As[r][c4] = *(const float4*)(A + (size_t)(row0 + r) * Dm + k0 + c4);
        }
#pragma unroll
        for (int q2 = 0; q2 < 2; ++q2) {
            int oc = q2 * 256 + tid;
            int r = oc >> 4, c4 = (oc & 15) << 2;
            *(float4*)&Ws[r][c4] = *(const float4*)(W + (size_t)(k0 + r) * DRr + col0 + c4);
        }
        __syncthreads();
#pragma unroll 8
        for (int kk = 0; kk < 32; ++kk) {
            float a[4];
#pragma unroll
            for (int i = 0; i < 4; ++i) a[i] = As[tr * 4 + i][kk];
            float4 bv = *(const float4*)&Ws[kk][tc * 4];
            float b[4] = {bv.x, bv.y, bv.z, bv.w};
#pragma unroll
            for (int i = 0; i < 4; ++i)
#pragma unroll
                for (int j = 0; j < 4; ++j)
                    acc[i][j] = fmaf(a[i], b[j], acc[i][j]);
        }
    }
    float* Pz = P + (size_t)blockIdx.z * Mrows * DRr;
#pragma unroll
    for (int i = 0; i < 4; ++i) {
        int r = row0 + tr * 4 + i;
        float4 ov = {acc[i][0], acc[i][1], acc[i][2], acc[i][3]};
        *(float4*)(Pz + (size_t)r * DRr + col0 + tc * 4) = ov;
    }
}

// ---------------------------------------------------------------------------
// Reduce split-K partials (fixed order) + bias -> vqb f32 and vq_hi bf16.
// ---------------------------------------------------------------------------
__global__ __launch_bounds__(256)
void reduce_vq(const float* __restrict__ P, const float* __restrict__ bias,
               float* __restrict__ vqb, unsigned short* __restrict__ vq_hi)
{
    const size_t i4 = ((size_t)blockIdx.x * 256 + threadIdx.x) * 4;
    const int col = (int)(i4 & 127);
    const size_t stride = (size_t)Mrows * DRr;
    float4 s = *(const float4*)(P + i4);
#pragma unroll
    for (int z = 1; z < 4; ++z) {
        float4 p = *(const float4*)(P + stride * z + i4);
        s.x += p.x; s.y += p.y; s.z += p.z; s.w += p.w;
    }
    float4 bv = *(const float4*)(bias + col);
    s.x += bv.x; s.y += bv.y; s.z += bv.z; s.w += bv.w;
    *(float4*)(vqb + i4) = s;
    uint2 u;
    u.x = pk_bf16(s.x, s.y);
    u.y = pk_bf16(s.z, s.w);
    *(uint2*)(vq_hi + i4) = u;
}

// ---------------------------------------------------------------------------
// Screen: A-resident col-sweep, NO atomics. (Unchanged from R15.)
// ---------------------------------------------------------------------------
__global__ __launch_bounds__(512)
void sim_max(const unsigned short* __restrict__ vq_hi,
             const unsigned short* __restrict__ vk_hi,
             float* __restrict__ rtm)
{
    __shared__ __align__(16) unsigned short Buf[2][64 * 128];   // 32KB dbuf
    const int tid = threadIdx.x;
    const int l = tid & 63, w = tid >> 6;
    const int l15 = l & 15, l4 = l >> 4;
    const int row0 = blockIdx.y * 128;
    const int key0 = blockIdx.x * 512;

    bf16x8 af[4];
    {
        const unsigned short* ap = vq_hi + (size_t)(row0 + w * 16 + l15) * 128 + l4 * 8;
#pragma unroll
        for (int kk = 0; kk < 4; ++kk) af[kk] = *(const bf16x8*)(ap + kk * 32);
    }

#pragma unroll
    for (int q2 = 0; q2 < 2; ++q2) {
        int oc = q2 * 512 + tid;
        int r = oc >> 4, pc = oc & 15;
        int lc = pc ^ (r & 15);
        uint4 vv = *(const uint4*)(vk_hi + (size_t)(key0 + r) * 128 + lc * 8);
        *(uint4*)&Buf[0][oc * 8] = vv;
    }
    __syncthreads();

    float tmax[4];

    for (int t = 0; t < 8; ++t) {
        const int cur = t & 1;
        uint4 st[2];
        if (t + 1 < 8) {
#pragma unroll
            for (int q2 = 0; q2 < 2; ++q2) {
                int oc = q2 * 512 + tid;
                int r = oc >> 4, pc = oc & 15;
                int lc = pc ^ (r & 15);
                st[q2] = *(const uint4*)(vk_hi + (size_t)(key0 + (t + 1) * 64 + r) * 128 + lc * 8);
            }
        }
        f32x4 acc[4];
#pragma unroll
        for (int ni = 0; ni < 4; ++ni) {
            const int key16 = ni * 16 + l15;
            bf16x8 bfr[4];
#pragma unroll
            for (int kk = 0; kk < 4; ++kk)
                bfr[kk] = *(bf16x8*)&Buf[cur][key16 * 128 + (((kk * 4 + l4) ^ (key16 & 15)) * 8)];
            f32x4 a = (f32x4)(0.f);
#pragma unroll
            for (int kk = 0; kk < 4; ++kk)
                a = __builtin_amdgcn_mfma_f32_16x16x32_bf16(af[kk], bfr[kk], a, 0, 0, 0);
            acc[ni] = a;
        }
        float tm[4];
#pragma unroll
        for (int j = 0; j < 4; ++j)
            tm[j] = fmaxf(fmaxf(acc[0][j], acc[1][j]), fmaxf(acc[2][j], acc[3][j]));
#pragma unroll
        for (int off = 1; off < 16; off <<= 1)
#pragma unroll
            for (int j = 0; j < 4; ++j)
                tm[j] = fmaxf(tm[j], __shfl_xor(tm[j], off));
        if ((t & 1) == 0) {
#pragma unroll
            for (int j = 0; j < 4; ++j) tmax[j] = tm[j];
        } else {
            if (l15 == 0) {
                const size_t tbase = (size_t)(blockIdx.x * 4 + (t >> 1)) * Mrows;
#pragma unroll
                for (int j = 0; j < 4; ++j)
                    rtm[tbase + row0 + w * 16 + l4 * 4 + j] = fmaxf(tmax[j], tm[j]);
            }
        }
        if (t + 1 < 8) {
#pragma unroll
            for (int q2 = 0; q2 < 2; ++q2) {
                int oc = q2 * 512 + tid;
                *(uint4*)&Buf[cur ^ 1][oc * 8] = st[q2];
            }
        }
        __syncthreads();
    }
}

// ---------------------------------------------------------------------------
// thr[row] = max over 64 tile-maxima - MARGIN (rtm transposed: [tile][row]).
// ---------------------------------------------------------------------------
__global__ __launch_bounds__(256)
void sim_combine2(const float* __restrict__ rtm, float* __restrict__ thr)
{
    int r = blockIdx.x * 256 + threadIdx.x;
    if (r >= Mrows) return;
    float m = -INFINITY;
#pragma unroll 8
    for (int c = 0; c < 64; ++c)
        m = fmaxf(m, rtm[(size_t)c * Mrows + r]);
    thr[r] = m - MARGIN;
}

// ---------------------------------------------------------------------------
// Collect qualifying (row,tile) pairs (ballot-aggregated pushes).
// ---------------------------------------------------------------------------
__global__ __launch_bounds__(256)
void collect_pairs(const float* __restrict__ rtm, const float* __restrict__ thr,
                   unsigned* __restrict__ cnt, unsigned* __restrict__ pairs)
{
    const int idx = blockIdx.x * 256 + threadIdx.x;
    const int tile = idx >> 12, row = idx & 4095;
    const bool pred = rtm[(size_t)tile * Mrows + row] >= thr[row];
    unsigned long long mask = __ballot(pred);
    if (mask) {
        const int lane = threadIdx.x & 63;
        const int leader = __ffsll((long long)mask) - 1;
        unsigned base = 0;
        if (lane == leader) base = atomicAdd(cnt, (unsigned)__popcll(mask));
        base = (unsigned)__shfl((int)base, leader);
        if (pred) {
            unsigned off = (unsigned)__popcll(mask & ((1ull << lane) - 1ull));
            pairs[base + off] = ((unsigned)row << 6) | (unsigned)tile;
        }
    }
}

// ---------------------------------------------------------------------------
// Exact f32 rescore, one block per (row,tile) pair (grid-stride).
// ---------------------------------------------------------------------------
__global__ __launch_bounds__(256)
void rescore_pair(const unsigned* __restrict__ pairs, const unsigned* __restrict__ cnt,
                  const float* __restrict__ vq, const float* __restrict__ vkeys,
                  unsigned long long* __restrict__ best)
{
    __shared__ float vqs[128];
    __shared__ float part[256];
    const int tid = threadIdx.x;
    const unsigned n = min(*cnt, (unsigned)CAP);
    for (unsigned i = blockIdx.x; i < n; i += gridDim.x) {
        const unsigned p = pairs[i];
        const unsigned row = p >> 6, tile = p & 63u;
        if (tid < 32) {
            float4 v = *(const float4*)(vq + (size_t)row * 128 + tid * 4);
            *(float4*)&vqs[tid * 4] = v;
        }
        __syncthreads();
        const int k = tid & 127, h = (tid >> 7) * 64;
        const float* kp = vkeys + (size_t)(tile * 128 + k) * 128 + h;
        float s = 0.f;
#pragma unroll
        for (int d = 0; d < 64; d += 4) {
            float4 kv = *(const float4*)(kp + d);
            s = fmaf(vqs[h + d + 0], kv.x, s);
            s = fmaf(vqs[h + d + 1], kv.y, s);
            s = fmaf(vqs[h + d + 2], kv.z, s);
            s = fmaf(vqs[h + d + 3], kv.w, s);
        }
        part[tid] = s;
        __syncthreads();
        if (tid < 64) {
            float s0 = part[tid] + part[tid + 128];
            float s1 = part[tid + 64] + part[tid + 192];
            float bs = s0; int bk = tid;
            if (s1 > s0) { bs = s1; bk = tid + 64; }
#pragma unroll
            for (int off = 1; off < 64; off <<= 1) {
                float os = __shfl_xor(bs, off);
                int ok = __shfl_xor(bk, off);
                if (os > bs || (os == bs && ok < bk)) { bs = os; bk = ok; }
            }
            if (tid == 0) {
                unsigned key = tile * 128 + bk;
                unsigned fb = __float_as_uint(bs);
                fb = (fb & 0x80000000u) ? ~fb : (fb | 0x80000000u);
                unsigned long long enc = ((unsigned long long)fb << 32) | (unsigned)(~key);
                atomicMax(best + row, enc);
            }
        }
        __syncthreads();
    }
}

// ---------------------------------------------------------------------------
// Fused build + transpose: VT[(b*16+h)*64 + d][key] = bf16(hs * vembed[idx]).
// ---------------------------------------------------------------------------
__global__ __launch_bounds__(256)
void build_vt(const float* __restrict__ hs, const float* __restrict__ vembed,
              const unsigned long long* __restrict__ best,
              unsigned short* __restrict__ vt)
{
    __shared__ unsigned short T[64][73];
    __shared__ int ids[64];
    const int tid = threadIdx.x;
    const int kt = blockIdx.x;
    const int bh = blockIdx.y;
    const int b = bh >> 4, h = bh & 15;
    if (tid < 64) {
        int row = b * Ss + kt * 64 + tid;
        ids[tid] = (int)((~(unsigned)(best[row] & 0xFFFFFFFFull)) & 8191u);
    }
    __syncthreads();
    {
        int r = tid >> 2, c16 = (tid & 3) * 16;
        size_t hrow = (size_t)(b * Ss + kt * 64 + r) * Dm + h * HDd + c16;
        size_t erow = (size_t)ids[r] * Dm + h * HDd + c16;
#pragma unroll
        for (int q2 = 0; q2 < 4; ++q2) {
            float4 a = *(const float4*)(hs + hrow + q2 * 4);
            float4 e = *(const float4*)(vembed + erow + q2 * 4);
            T[r][c16 + q2 * 4 + 0] = f2bf(a.x * e.x);
            T[r][c16 + q2 * 4 + 1] = f2bf(a.y * e.y);
            T[r][c16 + q2 * 4 + 2] = f2bf(a.z * e.z);
            T[r][c16 + q2 * 4 + 3] = f2bf(a.w * e.w);
        }
    }
    __syncthreads();
    {
        int d = tid >> 2, kc = (tid & 3) * 16;
        unsigned short ob[16];
#pragma unroll
        for (int i = 0; i < 16; ++i) ob[i] = T[kc + i][d];
        unsigned short* op = vt + ((size_t)(b * Hh + h) * HDd + d) * Ss + kt * 64 + kc;
        *(uint4*)op = *(uint4*)&ob[0];
        *(uint4*)(op + 8) = *(uint4*)&ob[8];
    }
}

// ---------------------------------------------------------------------------
// meanv[b][h*64+d] from VT row sums (fully-masked-row substitution value).
// ---------------------------------------------------------------------------
__global__ __launch_bounds__(256)
void mean_vt(const unsigned short* __restrict__ vt, float* __restrict__ mv)
{
    const int bh = blockIdx.x;
    const int b = bh >> 4, h = bh & 15;
    const int d = threadIdx.x >> 2, part = threadIdx.x & 3;
    const unsigned short* row = vt + ((size_t)bh * HDd + d) * Ss + part * 512;
    float s = 0.f;
    for (int j = 0; j < 512; j += 8) {
        uint4 u = *(const uint4*)(row + j);
        const unsigned uu[4] = {u.x, u.y, u.z, u.w};
#pragma unroll
        for (int m = 0; m < 4; ++m) {
            s += bf2f((unsigned short)(uu[m] & 0xffff));
            s += bf2f((unsigned short)(uu[m] >> 16));
        }
    }
    s += __shfl_xor(s, 1);
    s += __shfl_xor(s, 2);
    if (part == 0) mv[b * Dm + h * HDd + d] = s * (1.f / 2048.f);
}

// ---------------------------------------------------------------------------
// bf16 MFMA flash attention v5 (unchanged from R15, proven at 52.6 us).
// ---------------------------------------------------------------------------
__global__ __launch_bounds__(512)
void attn_mfma5(const unsigned short* __restrict__ q, const unsigned short* __restrict__ k,
                const unsigned short* __restrict__ vt, const float* __restrict__ am,
                const float* __restrict__ dmask, const float* __restrict__ meanv,
                unsigned short* __restrict__ o)
{
    __shared__ __align__(16) unsigned char smem[57344]; // K dbuf 16K | VT dbuf 16K | P 16K | amdm 8K
    __shared__ float uniflag[128];
    unsigned char* Psm = smem + 32768;
    float* amdmf = (float*)(smem + 49152);

    const int tid = threadIdx.x;
    const int l = tid & 63, w = tid >> 6;
    const int l15 = l & 15, l4 = l >> 4;
    const int lin = blockIdx.x + (blockIdx.y << 4) + (blockIdx.z << 8);
    const int half = lin >> 8, rem = lin & 255;
    const int qtb = rem & 15;
    const int qt = half ? (15 - qtb) : qtb;
    const int h = rem >> 4;
    const int b = half;
    const int row0 = qt * 128;

    {   // mask table: 0 or MIN_D per key
        int j = tid * 4;
        float4 a = *(const float4*)(am + b * Ss + j);
        float4 d = *(const float4*)(dmask + h * Ss + j);
        float4 m;
        m.x = (a.x * d.x == 0.f) ? MIN_D : 0.f;
        m.y = (a.y * d.y == 0.f) ? MIN_D : 0.f;
        m.z = (a.z * d.z == 0.f) ? MIN_D : 0.f;
        m.w = (a.w * d.w == 0.f) ? MIN_D : 0.f;
        *(float4*)&amdmf[j] = m;
    }

    const int qloc = w * 16 + l15;
    const int qrow = row0 + qloc;
    bf16x8 qf[2];
    {
        const unsigned short* qp = q + ((size_t)(b * Ss + qrow)) * Dm + h * HDd + l4 * 8;
        qf[0] = *(const bf16x8*)qp;
        qf[1] = *(const bf16x8*)(qp + 32);
    }

    const int skey = tid >> 3, spc = tid & 7;
    const int slk = spc ^ (skey & 7);
    const int svd = tid >> 3;
    const int slv = spc ^ (svd & 7);

    {
        uint4 kv = *(const uint4*)(k + ((size_t)(b * Ss + skey)) * Dm + h * HDd + slk * 8);
        *(uint4*)&smem[tid * 16] = kv;
        uint4 vv = *(const uint4*)(vt + ((size_t)(b * Hh + h) * HDd + svd) * Ss + slv * 8);
        *(uint4*)&smem[16384 + tid * 16] = vv;
    }
    __syncthreads();

    f32x4 acc[4];
#pragma unroll
    for (int d2 = 0; d2 < 4; ++d2) acc[d2] = (f32x4)(0.f);
    float mrun = -INFINITY, lrun = 0.f;
    const int ktmax = 2 * qt + 1;

    for (int kt = 0; kt <= ktmax; ++kt) {
        const unsigned cb = (unsigned)(kt & 1) << 13;
        unsigned char* Ksm = smem + cb;
        unsigned char* Vsm = smem + 16384 + cb;
        uint4 kst, vst;
        if (kt < ktmax) {
            kst = *(const uint4*)(k + ((size_t)(b * Ss + (kt + 1) * 64 + skey)) * Dm
                                  + h * HDd + slk * 8);
            vst = *(const uint4*)(vt + ((size_t)(b * Hh + h) * HDd + svd) * Ss
                                  + (kt + 1) * 64 + slv * 8);
        }

        f32x4 sreg[4];
#pragma unroll
        for (int kb = 0; kb < 4; ++kb) {
            const int key16 = kb * 16 + l15;
            const int sw = key16 & 7;
            bf16x8 k0 = *(bf16x8*)&Ksm[key16 * 128 + ((l4 ^ sw) * 16)];
            bf16x8 k1 = *(bf16x8*)&Ksm[key16 * 128 + (((4 + l4) ^ sw) * 16)];
            f32x4 s = (f32x4)(0.f);
            s = __builtin_amdgcn_mfma_f32_16x16x32_bf16(k0, qf[0], s, 0, 0, 0);
            s = __builtin_amdgcn_mfma_f32_16x16x32_bf16(k1, qf[1], s, 0, 0, 0);
            sreg[kb] = s;
        }

        float sv[16];
#pragma unroll
        for (int kb = 0; kb < 4; ++kb)
#pragma unroll
            for (int r = 0; r < 4; ++r) {
                const int key = kt * 64 + kb * 16 + l4 * 4 + r;
                const float mval = (key > qrow) ? MIN_D : amdmf[key];
                sv[kb * 4 + r] = fmaf(sreg[kb][r], C2, mval);
            }

        float pm = fmaxf(fmaxf(sv[0], sv[1]), sv[2]);
        pm = fmaxf(fmaxf(pm, sv[3]), fmaxf(sv[4], sv[5]));
        pm = fmaxf(fmaxf(pm, sv[6]), fmaxf(sv[7], sv[8]));
        pm = fmaxf(fmaxf(pm, sv[9]), fmaxf(sv[10], sv[11]));
        pm = fmaxf(fmaxf(pm, sv[12]), fmaxf(sv[13], sv[14]));
        pm = fmaxf(pm, sv[15]);
        pm = fmaxf(pm, __shfl_xor(pm, 16));
        pm = fmaxf(pm, __shfl_xor(pm, 32));

        if (__any(pm > mrun + 8.f)) {
            const float mn = fmaxf(mrun, pm);
            const float sc = __builtin_amdgcn_exp2f(mrun - mn);
            lrun *= sc;
#pragma unroll
            for (int d2 = 0; d2 < 4; ++d2) acc[d2] *= sc;
            mrun = mn;
        }

        float p[16], rs = 0.f;
#pragma unroll
        for (int i = 0; i < 16; ++i) {
            p[i] = __builtin_amdgcn_exp2f(sv[i] - mrun);
            rs += p[i];
        }
        rs += __shfl_xor(rs, 16);
        rs += __shfl_xor(rs, 32);
        lrun += rs;

        const unsigned pswz = (l15 & 7) << 4;
#pragma unroll
        for (int kb = 0; kb < 4; ++kb) {
            uint2 u;
            u.x = pk_bf16(p[kb * 4 + 0], p[kb * 4 + 1]);
            u.y = pk_bf16(p[kb * 4 + 2], p[kb * 4 + 3]);
            *(uint2*)&Psm[qloc * 128 + ((kb * 32 + l4 * 8) ^ pswz)] = u;
        }

#pragma unroll
        for (int ks = 0; ks < 2; ++ks) {
            bf16x8 pa = *(bf16x8*)&Psm[qloc * 128 + ((ks * 64 + l4 * 16) ^ pswz)];
#pragma unroll
            for (int d2 = 0; d2 < 4; ++d2) {
                const int dd = d2 * 16 + l15;
                bf16x8 vb = *(bf16x8*)&Vsm[dd * 128 + ((ks * 64 + l4 * 16) ^ ((dd & 7) << 4))];
                acc[d2] = __builtin_amdgcn_mfma_f32_16x16x32_bf16(vb, pa, acc[d2], 0, 0, 0);
            }
        }

        if (kt < ktmax) {
            const unsigned nb = cb ^ 8192u;
            *(uint4*)&smem[nb + tid * 16] = kst;
            *(uint4*)&smem[16384 + nb + tid * 16] = vst;
        }
        __syncthreads();
    }

    const float inv = 1.f / lrun;
    const bool uni = (mrun <= -1e37f);
    unsigned short* stg = (unsigned short*)smem;
    uniflag[qloc] = uni ? 1.f : 0.f;
#pragma unroll
    for (int d2 = 0; d2 < 4; ++d2) {
        uint2 u;
        u.x = pk_bf16(acc[d2][0] * inv, acc[d2][1] * inv);
        u.y = pk_bf16(acc[d2][2] * inv, acc[d2][3] * inv);
        *(uint2*)&stg[qloc * 72 + d2 * 16 + l4 * 4] = u;
    }
    __syncthreads();
    {
        const int r = tid >> 2, c16 = (tid & 3) * 16;
        const bool u = uniflag[r] != 0.f;
        uint4 o0, o1;
        if (u) {
            unsigned short ob[16];
#pragma unroll
            for (int i = 0; i < 16; ++i)
                ob[i] = f2bf(meanv[b * Dm + h * HDd + c16 + i]);
            o0 = *(uint4*)&ob[0];
            o1 = *(uint4*)&ob[8];
        } else {
            o0 = *(uint4*)&stg[r * 72 + c16];
            o1 = *(uint4*)&stg[r * 72 + c16 + 8];
        }
        unsigned short* op = o + ((size_t)(b * Ss + row0 + r)) * Dm + h * HDd + c16;
        *(uint4*)op = o0;
        *(uint4*)(op + 8) = o1;
    }
}

// ---------------------------------------------------------------------------
extern "C" void kernel_launch(void* const* d_in, const int* in_sizes, int n_in,
                              void* d_out, int out_size, void* d_ws, size_t ws_size,
                              hipStream_t stream)
{
    const float* hs     = (const float*)d_in[0];
    const float* amask  = (const float*)d_in[1];
    const float* Wq     = (const float*)d_in[2];
    const float* bq     = (const float*)d_in[3];
    const float* Wk     = (const float*)d_in[4];
    const float* bk     = (const float*)d_in[5];
    const float* dmask  = (const float*)d_in[6];
    const float* Wvq    = (const float*)d_in[7];
    const float* bvq    = (const float*)d_in[8];
    const float* vkeys  = (const float*)d_in[9];
    const float* vembed = (const float*)d_in[10];
    const float* Wo     = (const float*)d_in[11];
    const float* bo     = (const float*)d_in[12];
    float* out = (float*)d_out;

    char* w = (char*)d_ws;
    size_t off = 0;
    auto take = [&](size_t n) { char* p = w + off; off = (off + n + 255) & ~(size_t)255; return p; };
    unsigned short* hsbf  = (unsigned short*)take((size_t)Mrows * Dm * 2);
    unsigned short* WqT   = (unsigned short*)take((size_t)Dm * Dm * 2);
    unsigned short* WkT   = (unsigned short*)take((size_t)Dm * Dm * 2);
    unsigned short* WoT   = (unsigned short*)take((size_t)Dm * Dm * 2);
    unsigned short* qbf   = (unsigned short*)take((size_t)Mrows * Dm * 2);
    unsigned short* kbf   = (unsigned short*)take((size_t)Mrows * Dm * 2);
    unsigned short* vtb   = (unsigned short*)take((size_t)Mrows * Dm * 2);   // VT
    unsigned short* attno = (unsigned short*)take((size_t)Mrows * Dm * 2);
    float* vqp   = (float*)take((size_t)4 * Mrows * DRr * 4);               // split-K partials
    float* vqb   = (float*)take((size_t)Mrows * DRr * 4);
    unsigned short* vq_hi = (unsigned short*)take((size_t)Mrows * DRr * 2);
    unsigned short* vk_hi = (unsigned short*)take((size_t)NV * DRr * 2);
    float* rtm   = (float*)take((size_t)64 * Mrows * 4);                    // [tile][row]
    float* thr   = (float*)take((size_t)Mrows * 4);
    unsigned* cnt = (unsigned*)take(256);
    unsigned* pairs = (unsigned*)take((size_t)CAP * 4);
    unsigned long long* best = (unsigned long long*)take((size_t)Mrows * 8);
    float* mvb   = (float*)take((size_t)Bb * Dm * 4);

    (void)hipMemsetAsync(cnt, 0, 4, stream);
    (void)hipMemsetAsync(best, 0, (size_t)Mrows * 8, stream);

    dim3 blk(256);
    // dtype prep
    cvt_bf16<<<dim3(Mrows * Dm / 2048), blk, 0, stream>>>(hs, hsbf);
    transpose_cvt3<<<dim3(Dm / 64, Dm / 64, 3), blk, 0, stream>>>(Wq, Wk, Wo, WqT, WkT, WoT);
    // Q,K projections fused via z (dbuf+T14 GEMM)
    gemm_bf16<true><<<dim3(Dm / 128, Mrows / 128, 2), dim3(512), 0, stream>>>(
        hsbf, WqT, WkT, bq, bk, qbf, kbf, Dm, Dm);
    // retrieval: split-K exact vq, reduce(+bf16 copy), A-resident max screen,
    // pair collection, exact per-pair rescore
    gemm_vq_partial<<<dim3(DRr / 64, Mrows / 64, 4), blk, 0, stream>>>(hs, Wvq, vqp);
    reduce_vq<<<dim3(Mrows * DRr / 1024), blk, 0, stream>>>(vqp, bvq, vqb, vq_hi);
    cvt_bf16<<<dim3(NV * DRr / 2048), blk, 0, stream>>>(vkeys, vk_hi);
    sim_max<<<dim3(NV / 512, Mrows / 128), dim3(512), 0, stream>>>(vq_hi, vk_hi, rtm);
    sim_combine2<<<dim3(Mrows / 256), blk, 0, stream>>>(rtm, thr);
    collect_pairs<<<dim3(64 * Mrows / 256), blk, 0, stream>>>(rtm, thr, cnt, pairs);
    rescore_pair<<<dim3(2048), blk, 0, stream>>>(pairs, cnt, vqb, vkeys, best);
    // fused build+transpose of V, then mean
    build_vt<<<dim3(Ss / 64, Bb * Hh), blk, 0, stream>>>(hs, vembed, best, vtb);
    mean_vt<<<dim3(Bb * Hh), blk, 0, stream>>>(vtb, mvb);
    // attention (512 threads, double-buffered)
    attn_mfma5<<<dim3(Ss / 128, Hh, Bb), dim3(512), 0, stream>>>(
        qbf, kbf, vtb, amask, dmask, mvb, attno);
    // output projection (f32 out, dbuf+T14 GEMM)
    gemm_bf16<false><<<dim3(Dm / 128, Mrows / 128, 1), dim3(512), 0, stream>>>(
        attno, WoT, WoT, bo, bo, out, out, Dm, Dm);
}